// Round 2
// baseline (2276.933 us; speedup 1.0000x reference)
//
#include <hip/hip_runtime.h>
#include <stdint.h>

#define NEG_SLOPE 0.2f
#define BN_EPS 1e-5f

typedef unsigned short u16;
typedef unsigned int   u32;

__device__ __forceinline__ float lrelu(float x){ return fmaxf(x, NEG_SLOPE*x); }
__device__ __forceinline__ float bf2f(u16 u){ return __uint_as_float(((u32)u) << 16); }
__device__ __forceinline__ u16 f2bf(float f){           // round-to-nearest-even
  u32 u = __float_as_uint(f);
  return (u16)((u + 0x7fffu + ((u >> 16) & 1u)) >> 16);
}

// ---------------- misc ----------------
__global__ __launch_bounds__(256) void zero_int_k(int* __restrict__ p, int n){
  int t = blockIdx.x*256 + threadIdx.x;
  if (t < n) p[t] = 0;
}

// ---------------- CSR build (per-graph topology, shared across batch) ----------------
__global__ __launch_bounds__(256) void hist_k(const int* __restrict__ dst, int* __restrict__ counts, int n){
  int t = blockIdx.x*256 + threadIdx.x;
  if (t < n) atomicAdd(&counts[dst[t]], 1);
}

__global__ __launch_bounds__(1024) void scan_k(const int* __restrict__ counts, int* __restrict__ indptr,
                                               int* __restrict__ cursor, int n){
  __shared__ int part[1024];
  int tid = threadIdx.x;
  int base = tid*4;
  int v0 = (base+0<n)?counts[base+0]:0;
  int v1 = (base+1<n)?counts[base+1]:0;
  int v2 = (base+2<n)?counts[base+2]:0;
  int v3 = (base+3<n)?counts[base+3]:0;
  part[tid] = v0+v1+v2+v3;
  __syncthreads();
  for (int off=1; off<1024; off<<=1){
    int t2 = (tid>=off)?part[tid-off]:0;
    __syncthreads();
    part[tid] += t2;
    __syncthreads();
  }
  int run = (tid>0)?part[tid-1]:0;
  if (base+0<n){ indptr[base+0]=run; cursor[base+0]=run; run+=v0; }
  if (base+1<n){ indptr[base+1]=run; cursor[base+1]=run; run+=v1; }
  if (base+2<n){ indptr[base+2]=run; cursor[base+2]=run; run+=v2; }
  if (base+3<n){ indptr[base+3]=run; cursor[base+3]=run; run+=v3; }
  if (tid==0) indptr[n] = part[1023];
}

__global__ __launch_bounds__(256) void scatter_k(const int* __restrict__ src, const int* __restrict__ dstl,
                         int* __restrict__ cursor, int* __restrict__ colv, int* __restrict__ rowof, int n){
  int t = blockIdx.x*256 + threadIdx.x;
  if (t < n){
    int dd = dstl[t];
    int p = atomicAdd(&cursor[dd], 1);
    colv[p] = src[t];
    rowof[p] = dd;
  }
}

// ---------------- layer-0 GEMM: x[n,3] @ W0[3,64] -> h bf16, al_s, al_d ----------------
__global__ __launch_bounds__(256) void gemm3_k(const float* __restrict__ x, const float* __restrict__ Wg,
                        const float* __restrict__ asrc, const float* __restrict__ adst,
                        u16* __restrict__ h, float* __restrict__ als, float* __restrict__ ald, int nrows)
{
  const int l = threadIdx.x & 63;
  float W0 = Wg[l], W1 = Wg[64+l], W2 = Wg[128+l];
  const float as_l = asrc[l], ad_l = adst[l];
  int gw = blockIdx.x*4 + (threadIdx.x>>6);
  int stride = gridDim.x*4;
  for (int r = gw; r < nrows; r += stride){
    float x0 = x[(size_t)r*3+0];
    float x1 = x[(size_t)r*3+1];
    float x2 = x[(size_t)r*3+2];
    float acc = fmaf(x0, W0, fmaf(x1, W1, x2*W2));
    h[(size_t)r*64 + l] = f2bf(acc);
    float s = acc*as_l, dsum = acc*ad_l;
    #pragma unroll
    for (int o=32; o>0; o>>=1){ s += __shfl_xor(s,o); dsum += __shfl_xor(dsum,o); }
    if (l==0){ als[r]=s; ald[r]=dsum; }
  }
}

// ---------------- layers 1/2 GEMM: BN(P)[n,64] @ W[64,64] -> h bf16, al_s, al_d ----------------
__global__ __launch_bounds__(256) void gemm64_k(const u16* __restrict__ Pin, const float* __restrict__ Wg,
                        const float* __restrict__ asrc, const float* __restrict__ adst,
                        const float* __restrict__ bnstats,  // [128] = {mean[64], rstd[64]}
                        u16* __restrict__ h, float* __restrict__ als, float* __restrict__ ald, int nrows)
{
  const int l = threadIdx.x & 63;
  float Wreg[64];
  #pragma unroll
  for (int k=0;k<64;k++) Wreg[k] = Wg[k*64 + l];
  const float as_l = asrc[l], ad_l = adst[l];
  const float bm = bnstats[l], br = bnstats[64+l];
  int gw = blockIdx.x*4 + (threadIdx.x>>6);
  int stride = gridDim.x*4;
  for (int r = gw; r < nrows; r += stride){
    float xv = (bf2f(Pin[(size_t)r*64 + l]) - bm) * br;
    int xi = __float_as_int(xv);
    float acc0 = 0.f, acc1 = 0.f;
    #pragma unroll
    for (int k=0;k<64;k+=2){
      float b0 = __int_as_float(__builtin_amdgcn_readlane(xi, k));
      float b1 = __int_as_float(__builtin_amdgcn_readlane(xi, k+1));
      acc0 = fmaf(b0, Wreg[k],   acc0);
      acc1 = fmaf(b1, Wreg[k+1], acc1);
    }
    float acc = acc0 + acc1;
    h[(size_t)r*64 + l] = f2bf(acc);
    float s = acc*as_l, dsum = acc*ad_l;
    #pragma unroll
    for (int o=32; o>0; o>>=1){ s += __shfl_xor(s,o); dsum += __shfl_xor(dsum,o); }
    if (l==0){ als[r]=s; ald[r]=dsum; }
  }
}

// ---------------- per-edge unnormalized attention weight ----------------
__global__ __launch_bounds__(256) void edge_w_k(const int* __restrict__ colv, const int* __restrict__ rowof,
                         const float* __restrict__ als, const float* __restrict__ ald,
                         float* __restrict__ w, int log2E, int log2NS, int ntot)
{
  int t = blockIdx.x*256 + threadIdx.x;
  if (t >= ntot) return;
  int b   = t >> log2E;
  int pos = t & ((1<<log2E)-1);
  int s = colv[pos];
  int d = rowof[pos];
  int base = b << log2NS;
  float e = als[base + s] + ald[base + d];
  w[t] = __expf(lrelu(e));
}

// ---------------- GAT gather + softmax + bias + relu + pairwise max-pool ----------------
// wave per node PAIR (cluster = node//2), lane = feature. No atomics.
__global__ __launch_bounds__(256) void gat_pool_k(const u16* __restrict__ h, const float* __restrict__ als,
                      const float* __restrict__ ald, const float* __restrict__ bias,
                      const int* __restrict__ indptr, const int* __restrict__ colv,
                      const float* __restrict__ w, u16* __restrict__ P,
                      int log2NS, int log2E, int npairs)
{
  const int l = threadIdx.x & 63;
  int gw = blockIdx.x*4 + (threadIdx.x>>6);
  if (gw >= npairs) return;
  const int half = log2NS - 1;
  int b = gw >> half;
  int k = gw & ((1<<half)-1);
  const float bl = bias[l];
  size_t hgbase = ((size_t)b << log2NS) * 64;
  int wbase = b << log2E;
  int nbase = b << log2NS;
  float omax = 0.f;                       // both candidates are post-ReLU (>=0)
  #pragma unroll
  for (int j=0;j<2;j++){
    int d = 2*k + j;
    int g = nbase + d;
    float es = als[g] + ald[g];           // self-loop
    float wself = __expf(lrelu(es));
    float z = wself;
    float acc = wself * bf2f(h[(size_t)g*64 + l]);
    int p0 = indptr[d], p1 = indptr[d+1];
    for (int p=p0; p<p1; ++p){
      int s = colv[p];
      float wv = w[wbase + p];
      z += wv;
      acc = fmaf(wv, bf2f(h[hgbase + (size_t)s*64 + l]), acc);
    }
    float o = fmaxf(acc/z + bl, 0.f);
    omax = fmaxf(omax, o);
  }
  P[(size_t)gw*64 + l] = f2bf(omax);
}

// ---------------- BatchNorm stats (2-stage) ----------------
__global__ __launch_bounds__(256) void bn_stats_k(const u16* __restrict__ P, float* __restrict__ scratch, int nrows){
  const int l = threadIdx.x & 63;
  int gw = blockIdx.x*4 + (threadIdx.x>>6);
  int GW = gridDim.x*4;
  float s = 0.f, s2 = 0.f;
  for (int r = gw; r < nrows; r += GW){
    float v = bf2f(P[(size_t)r*64 + l]);
    s += v; s2 = fmaf(v, v, s2);
  }
  __shared__ float ls[256], ls2[256];
  ls[threadIdx.x] = s; ls2[threadIdx.x] = s2;
  __syncthreads();
  if (threadIdx.x < 64){
    float S  = ls[threadIdx.x] + ls[threadIdx.x+64] + ls[threadIdx.x+128] + ls[threadIdx.x+192];
    float S2 = ls2[threadIdx.x] + ls2[threadIdx.x+64] + ls2[threadIdx.x+128] + ls2[threadIdx.x+192];
    scratch[blockIdx.x*128 + threadIdx.x] = S;
    scratch[blockIdx.x*128 + 64 + threadIdx.x] = S2;
  }
}

__global__ __launch_bounds__(128) void bn_finish_k(const float* __restrict__ scratch, float* __restrict__ stats,
                                                   int nblocks, float invN){
  __shared__ float accs[128];
  int j = threadIdx.x;
  float s = 0.f;
  for (int b=0;b<nblocks;b++) s += scratch[b*128 + j];
  accs[j] = s;
  __syncthreads();
  if (j < 64){
    float m = accs[j]*invN;
    float var = accs[j+64]*invN - m*m;
    stats[j] = m;
    stats[64+j] = rsqrtf(var + BN_EPS);
  }
}

// ---------------- final BN apply: bf16 P -> f32 out ----------------
__global__ __launch_bounds__(256) void bn_apply_k(const u32* __restrict__ P2, const float* __restrict__ stats,
                                                  float4* __restrict__ out, int nq){  // nq = elems/4
  int t = blockIdx.x*256 + threadIdx.x;
  if (t >= nq) return;
  int l = (t*4) & 63;
  u32 v0 = P2[t*2], v1 = P2[t*2+1];
  float4 r;
  r.x = (__uint_as_float((v0 & 0xffffu) << 16) - stats[l+0]) * stats[64+l+0];
  r.y = (__uint_as_float( v0 & 0xffff0000u    ) - stats[l+1]) * stats[64+l+1];
  r.z = (__uint_as_float((v1 & 0xffffu) << 16) - stats[l+2]) * stats[64+l+2];
  r.w = (__uint_as_float( v1 & 0xffff0000u    ) - stats[l+3]) * stats[64+l+3];
  out[t] = r;
}

// ---------------- launcher ----------------
extern "C" void kernel_launch(void* const* d_in, const int* in_sizes, int n_in,
                              void* d_out, int out_size, void* d_ws, size_t ws_size,
                              hipStream_t stream)
{
  const float* x      = (const float*)d_in[0];
  const float* Wl[3]  = {(const float*)d_in[1], (const float*)d_in[7],  (const float*)d_in[13]};
  const float* asl[3] = {(const float*)d_in[2], (const float*)d_in[8],  (const float*)d_in[14]};
  const float* adl[3] = {(const float*)d_in[3], (const float*)d_in[9],  (const float*)d_in[15]};
  const float* bl[3]  = {(const float*)d_in[4], (const float*)d_in[10], (const float*)d_in[16]};
  const int*   el[3]  = {(const int*)d_in[5],   (const int*)d_in[11],   (const int*)d_in[17]};

  const int NS[4]  = {4096, 2048, 1024, 512};
  const int EPB[3] = {32768, 16384, 8192};
  const int LOG2NS[3] = {12, 11, 10};
  const int LOG2E[3]  = {15, 14, 13};
  const int BATCH = 256;

  char* ws = (char*)d_ws;
  size_t off = 0;
  auto alloc = [&](size_t bytes)->char*{
    char* p = ws + off; off += (bytes + 255) & ~(size_t)255; return p;
  };

  u16*   hbuf    = (u16*)alloc((size_t)BATCH*NS[0]*64*2);      // 128 MB, reused per layer
  u16*   Pbuf    = (u16*)alloc((size_t)BATCH*NS[1]*64*2);      //  64 MB, reused per layer
  float* wbuf    = (float*)alloc((size_t)BATCH*EPB[0]*4);      //  32 MB
  float* als     = (float*)alloc((size_t)BATCH*NS[0]*4);       //   4 MB
  float* ald     = (float*)alloc((size_t)BATCH*NS[0]*4);       //   4 MB
  float* scratch = (float*)alloc(256*128*4);                   // 128 KB
  float* stats   = (float*)alloc(384*4);
  int* counts_all = (int*)alloc((size_t)(NS[0]+NS[1]+NS[2])*4);      // contiguous -> one zero pass
  int* cursor_all = (int*)alloc((size_t)(NS[0]+NS[1]+NS[2])*4);
  int *counts[3], *cursor[3], *indptr[3], *colv[3], *rowof[3];
  counts[0]=counts_all; counts[1]=counts_all+NS[0]; counts[2]=counts_all+NS[0]+NS[1];
  cursor[0]=cursor_all; cursor[1]=cursor_all+NS[0]; cursor[2]=cursor_all+NS[0]+NS[1];
  for (int i=0;i<3;i++){
    indptr[i] = (int*)alloc((size_t)(NS[i]+1)*4);
    colv[i]   = (int*)alloc((size_t)EPB[i]*4);
    rowof[i]  = (int*)alloc((size_t)EPB[i]*4);
  }
  if (off > ws_size) return;   // clean bail -> visible absmax failure, not a fault

  // ---- CSR builds ----
  int ctot = NS[0]+NS[1]+NS[2];
  zero_int_k<<<(ctot+255)/256, 256, 0, stream>>>(counts_all, ctot);
  for (int i=0;i<3;i++){
    int nb = EPB[i]/256;
    hist_k<<<nb, 256, 0, stream>>>(el[i] + EPB[i], counts[i], EPB[i]);
    scan_k<<<1, 1024, 0, stream>>>(counts[i], indptr[i], cursor[i], NS[i]);
    scatter_k<<<nb, 256, 0, stream>>>(el[i], el[i] + EPB[i], cursor[i], colv[i], rowof[i], EPB[i]);
  }

  // ---- layers ----
  for (int i=0;i<3;i++){
    int ntot = BATCH*NS[i];
    int npairs = ntot/2;

    if (i==0)
      gemm3_k <<<2048, 256, 0, stream>>>(x, Wl[0], asl[0], adl[0], hbuf, als, ald, ntot);
    else
      gemm64_k<<<2048, 256, 0, stream>>>(Pbuf, Wl[i], asl[i], adl[i], stats + (i-1)*128,
                                         hbuf, als, ald, ntot);

    int ne = BATCH*EPB[i];
    edge_w_k<<<ne/256, 256, 0, stream>>>(colv[i], rowof[i], als, ald, wbuf, LOG2E[i], LOG2NS[i], ne);

    gat_pool_k<<<npairs/4, 256, 0, stream>>>(hbuf, als, ald, bl[i], indptr[i], colv[i], wbuf,
                                             Pbuf, LOG2NS[i], LOG2E[i], npairs);

    bn_stats_k<<<256, 256, 0, stream>>>(Pbuf, scratch, npairs);
    bn_finish_k<<<1, 128, 0, stream>>>(scratch, stats + i*128, 256, 1.0f/(float)npairs);
  }

  // ---- final BN materialization into d_out ----
  int nq = out_size/4;
  bn_apply_k<<<(nq+255)/256, 256, 0, stream>>>((const u32*)Pbuf, stats + 256, (float4*)d_out, nq);
}

// Round 3
// 1356.236 us; speedup vs baseline: 1.6789x; 1.6789x over previous
//
#include <hip/hip_runtime.h>
#include <stdint.h>

#define NEG_SLOPE 0.2f
#define BN_EPS 1e-5f

typedef unsigned short u16;
typedef unsigned int   u32;

__device__ __forceinline__ float lrelu(float x){ return fmaxf(x, NEG_SLOPE*x); }
__device__ __forceinline__ float bf2f(u16 u){ return __uint_as_float(((u32)u) << 16); }
__device__ __forceinline__ u16 f2bf(float f){           // round-to-nearest-even
  u32 u = __float_as_uint(f);
  return (u16)((u + 0x7fffu + ((u >> 16) & 1u)) >> 16);
}

// ---------------- misc ----------------
__global__ __launch_bounds__(256) void zero_int_k(int* __restrict__ p, int n){
  int t = blockIdx.x*256 + threadIdx.x;
  if (t < n) p[t] = 0;
}

// ---------------- CSR build (per-graph topology, shared across batch) ----------------
__global__ __launch_bounds__(256) void hist_k(const int* __restrict__ dst, int* __restrict__ counts, int n){
  int t = blockIdx.x*256 + threadIdx.x;
  if (t < n) atomicAdd(&counts[dst[t]], 1);
}

__global__ __launch_bounds__(1024) void scan_k(const int* __restrict__ counts, int* __restrict__ indptr,
                                               int* __restrict__ cursor, int n){
  __shared__ int part[1024];
  int tid = threadIdx.x;
  int base = tid*4;
  int v0 = (base+0<n)?counts[base+0]:0;
  int v1 = (base+1<n)?counts[base+1]:0;
  int v2 = (base+2<n)?counts[base+2]:0;
  int v3 = (base+3<n)?counts[base+3]:0;
  part[tid] = v0+v1+v2+v3;
  __syncthreads();
  for (int off=1; off<1024; off<<=1){
    int t2 = (tid>=off)?part[tid-off]:0;
    __syncthreads();
    part[tid] += t2;
    __syncthreads();
  }
  int run = (tid>0)?part[tid-1]:0;
  if (base+0<n){ indptr[base+0]=run; cursor[base+0]=run; run+=v0; }
  if (base+1<n){ indptr[base+1]=run; cursor[base+1]=run; run+=v1; }
  if (base+2<n){ indptr[base+2]=run; cursor[base+2]=run; run+=v2; }
  if (base+3<n){ indptr[base+3]=run; cursor[base+3]=run; run+=v3; }
  if (tid==0) indptr[n] = part[1023];
}

__global__ __launch_bounds__(256) void scatter_k(const int* __restrict__ src, const int* __restrict__ dstl,
                         int* __restrict__ cursor, int* __restrict__ colv, int* __restrict__ rowof, int n){
  int t = blockIdx.x*256 + threadIdx.x;
  if (t < n){
    int dd = dstl[t];
    int p = atomicAdd(&cursor[dd], 1);
    colv[p] = src[t];
    rowof[p] = dd;
  }
}

// ---------------- layer-0 GEMM: x[n,3] @ W0[3,64] -> h bf16, al_s, al_d ----------------
__global__ __launch_bounds__(256) void gemm3_k(const float* __restrict__ x, const float* __restrict__ Wg,
                        const float* __restrict__ asrc, const float* __restrict__ adst,
                        u16* __restrict__ h, float* __restrict__ als, float* __restrict__ ald, int nrows)
{
  const int l = threadIdx.x & 63;
  float W0 = Wg[l], W1 = Wg[64+l], W2 = Wg[128+l];
  const float as_l = asrc[l], ad_l = adst[l];
  int gw = blockIdx.x*4 + (threadIdx.x>>6);
  int stride = gridDim.x*4;
  for (int r = gw; r < nrows; r += stride){
    float x0 = x[(size_t)r*3+0];
    float x1 = x[(size_t)r*3+1];
    float x2 = x[(size_t)r*3+2];
    float acc = fmaf(x0, W0, fmaf(x1, W1, x2*W2));
    h[(size_t)r*64 + l] = f2bf(acc);
    float s = acc*as_l, dsum = acc*ad_l;
    #pragma unroll
    for (int o=32; o>0; o>>=1){ s += __shfl_xor(s,o); dsum += __shfl_xor(dsum,o); }
    if (l==0){ als[r]=s; ald[r]=dsum; }
  }
}

// ---------------- layers 1/2 GEMM: BN(P)[n,64] @ W[64,64] -> h bf16, al_s, al_d ----------------
__global__ __launch_bounds__(256) void gemm64_k(const u16* __restrict__ Pin, const float* __restrict__ Wg,
                        const float* __restrict__ asrc, const float* __restrict__ adst,
                        const float* __restrict__ bnstats,  // [128] = {mean[64], rstd[64]}
                        u16* __restrict__ h, float* __restrict__ als, float* __restrict__ ald, int nrows)
{
  const int l = threadIdx.x & 63;
  float Wreg[64];
  #pragma unroll
  for (int k=0;k<64;k++) Wreg[k] = Wg[k*64 + l];
  const float as_l = asrc[l], ad_l = adst[l];
  const float bm = bnstats[l], br = bnstats[64+l];
  int gw = blockIdx.x*4 + (threadIdx.x>>6);
  int stride = gridDim.x*4;
  for (int r = gw; r < nrows; r += stride){
    float xv = (bf2f(Pin[(size_t)r*64 + l]) - bm) * br;
    int xi = __float_as_int(xv);
    float acc0 = 0.f, acc1 = 0.f;
    #pragma unroll
    for (int k=0;k<64;k+=2){
      float b0 = __int_as_float(__builtin_amdgcn_readlane(xi, k));
      float b1 = __int_as_float(__builtin_amdgcn_readlane(xi, k+1));
      acc0 = fmaf(b0, Wreg[k],   acc0);
      acc1 = fmaf(b1, Wreg[k+1], acc1);
    }
    float acc = acc0 + acc1;
    h[(size_t)r*64 + l] = f2bf(acc);
    float s = acc*as_l, dsum = acc*ad_l;
    #pragma unroll
    for (int o=32; o>0; o>>=1){ s += __shfl_xor(s,o); dsum += __shfl_xor(dsum,o); }
    if (l==0){ als[r]=s; ald[r]=dsum; }
  }
}

// ---------------- per-edge unnormalized attention weight ----------------
__global__ __launch_bounds__(256) void edge_w_k(const int* __restrict__ colv, const int* __restrict__ rowof,
                         const float* __restrict__ als, const float* __restrict__ ald,
                         float* __restrict__ w, int log2E, int log2NS, int ntot)
{
  int t = blockIdx.x*256 + threadIdx.x;
  if (t >= ntot) return;
  int b   = t >> log2E;
  int pos = t & ((1<<log2E)-1);
  int s = colv[pos];
  int d = rowof[pos];
  int base = b << log2NS;
  float e = als[base + s] + ald[base + d];
  w[t] = __expf(lrelu(e));
}

// ---------------- GAT gather + softmax + bias + relu + pairwise max-pool ----------------
// wave per node PAIR; lanes = (half, group, octet): half = dest node of pair,
// each 8-lane group gathers one edge's full 64-feat row via dwordx4.
__global__ __launch_bounds__(256) void gat_pool_k(const u16* __restrict__ h, const float* __restrict__ als,
                      const float* __restrict__ ald, const float* __restrict__ bias,
                      const int* __restrict__ indptr, const int* __restrict__ colv,
                      const float* __restrict__ w, u16* __restrict__ P,
                      int log2NS, int log2E, int npairs, int emax)
{
  const int l    = threadIdx.x & 63;
  const int half = l >> 5;
  const int g    = (l >> 3) & 3;
  const int o    = l & 7;
  // XCD-aware swizzle: graph-contiguous chunks per XCD (gridDim.x multiple of 8)
  const int NB   = gridDim.x;
  const int bid  = blockIdx.x;
  const int lb   = (bid & 7) * (NB >> 3) + (bid >> 3);
  const int gw   = lb * 4 + (int)(threadIdx.x >> 6);
  if (gw >= npairs) return;

  const int hbits = log2NS - 1;
  const int b = gw >> hbits;
  const int k = gw & ((1 << hbits) - 1);
  const int d = 2 * k + half;                 // this half's destination node
  const int nbase = b << log2NS;
  const size_t hgbase = ((size_t)nbase) << 6; // elems
  const int wbase = b << log2E;

  const int p0 = indptr[d], p1 = indptr[d + 1];
  const int items = 1 + (p1 - p0);            // self + edges
  const int iters = (items + 3) >> 2;         // 4 groups per half

  const float ald_d = ald[nbase + d];
  const float als_d = als[nbase + d];
  const float wself = __expf(lrelu(als_d + ald_d));

  float acc0=0.f,acc1=0.f,acc2=0.f,acc3=0.f,acc4=0.f,acc5=0.f,acc6=0.f,acc7=0.f;
  float z = 0.f;

  // fetch (src, weight) for item it*4+g (software pipeline stage)
  auto fetch_sw = [&](int it, int& s_out, float& w_out){
    int qb = it * 4 + g;
    int p  = p0 + qb - 1;
    bool isedge = (qb >= 1) && (p < p1);
    int pp = isedge ? p : 0;
    if (pp > emax - 1) pp = emax - 1;
    int sv   = colv[pp];
    float wl = w[wbase + pp];
    s_out = (qb == 0) ? d : sv;
    w_out = (qb == 0) ? wself : (isedge ? wl : 0.f);
  };

  int s_cur; float w_cur;
  fetch_sw(0, s_cur, w_cur);
  for (int it = 0; it < iters; ++it){
    const u32* hp = (const u32*)(h + hgbase + ((size_t)s_cur << 6)) + (o << 2);
    u32 a0 = hp[0], a1 = hp[1], a2 = hp[2], a3 = hp[3];
    int s_nxt = s_cur; float w_nxt = 0.f;
    if (it + 1 < iters) fetch_sw(it + 1, s_nxt, w_nxt);
    float wv = w_cur;
    z += wv;
    acc0 = fmaf(wv, __uint_as_float(a0 << 16),         acc0);
    acc1 = fmaf(wv, __uint_as_float(a0 & 0xffff0000u), acc1);
    acc2 = fmaf(wv, __uint_as_float(a1 << 16),         acc2);
    acc3 = fmaf(wv, __uint_as_float(a1 & 0xffff0000u), acc3);
    acc4 = fmaf(wv, __uint_as_float(a2 << 16),         acc4);
    acc5 = fmaf(wv, __uint_as_float(a2 & 0xffff0000u), acc5);
    acc6 = fmaf(wv, __uint_as_float(a3 << 16),         acc6);
    acc7 = fmaf(wv, __uint_as_float(a3 & 0xffff0000u), acc7);
    s_cur = s_nxt; w_cur = w_nxt;
  }

  // reduce across the 4 groups within each half
  #pragma unroll
  for (int off = 8; off <= 16; off <<= 1){
    z    += __shfl_xor(z, off);
    acc0 += __shfl_xor(acc0, off);
    acc1 += __shfl_xor(acc1, off);
    acc2 += __shfl_xor(acc2, off);
    acc3 += __shfl_xor(acc3, off);
    acc4 += __shfl_xor(acc4, off);
    acc5 += __shfl_xor(acc5, off);
    acc6 += __shfl_xor(acc6, off);
    acc7 += __shfl_xor(acc7, off);
  }
  float rz = 1.0f / z;
  const float* bp = bias + (o << 3);
  float4 bA = *(const float4*)(bp);
  float4 bB = *(const float4*)(bp + 4);
  float q0 = fmaxf(fmaf(acc0, rz, bA.x), 0.f);
  float q1 = fmaxf(fmaf(acc1, rz, bA.y), 0.f);
  float q2 = fmaxf(fmaf(acc2, rz, bA.z), 0.f);
  float q3 = fmaxf(fmaf(acc3, rz, bA.w), 0.f);
  float q4 = fmaxf(fmaf(acc4, rz, bB.x), 0.f);
  float q5 = fmaxf(fmaf(acc5, rz, bB.y), 0.f);
  float q6 = fmaxf(fmaf(acc6, rz, bB.z), 0.f);
  float q7 = fmaxf(fmaf(acc7, rz, bB.w), 0.f);
  // pool the pair: max across halves
  q0 = fmaxf(q0, __shfl_xor(q0, 32));
  q1 = fmaxf(q1, __shfl_xor(q1, 32));
  q2 = fmaxf(q2, __shfl_xor(q2, 32));
  q3 = fmaxf(q3, __shfl_xor(q3, 32));
  q4 = fmaxf(q4, __shfl_xor(q4, 32));
  q5 = fmaxf(q5, __shfl_xor(q5, 32));
  q6 = fmaxf(q6, __shfl_xor(q6, 32));
  q7 = fmaxf(q7, __shfl_xor(q7, 32));
  u32 w0 = (u32)f2bf(q0) | ((u32)f2bf(q1) << 16);
  u32 w1 = (u32)f2bf(q2) | ((u32)f2bf(q3) << 16);
  u32 w2 = (u32)f2bf(q4) | ((u32)f2bf(q5) << 16);
  u32 w3 = (u32)f2bf(q6) | ((u32)f2bf(q7) << 16);
  if (l < 8){
    ((int4*)(P + ((size_t)gw << 6)))[o] = make_int4((int)w0,(int)w1,(int)w2,(int)w3);
  }
}

// ---------------- BatchNorm stats (2-stage) ----------------
__global__ __launch_bounds__(256) void bn_stats_k(const u16* __restrict__ P, float* __restrict__ scratch, int nrows){
  const int l = threadIdx.x & 63;
  int gw = blockIdx.x*4 + (threadIdx.x>>6);
  int GW = gridDim.x*4;
  float s = 0.f, s2 = 0.f;
  for (int r = gw; r < nrows; r += GW){
    float v = bf2f(P[(size_t)r*64 + l]);
    s += v; s2 = fmaf(v, v, s2);
  }
  __shared__ float ls[256], ls2[256];
  ls[threadIdx.x] = s; ls2[threadIdx.x] = s2;
  __syncthreads();
  if (threadIdx.x < 64){
    float S  = ls[threadIdx.x] + ls[threadIdx.x+64] + ls[threadIdx.x+128] + ls[threadIdx.x+192];
    float S2 = ls2[threadIdx.x] + ls2[threadIdx.x+64] + ls2[threadIdx.x+128] + ls2[threadIdx.x+192];
    scratch[blockIdx.x*128 + threadIdx.x] = S;
    scratch[blockIdx.x*128 + 64 + threadIdx.x] = S2;
  }
}

__global__ __launch_bounds__(128) void bn_finish_k(const float* __restrict__ scratch, float* __restrict__ stats,
                                                   int nblocks, float invN){
  __shared__ float accs[128];
  int j = threadIdx.x;
  float s = 0.f;
  for (int b=0;b<nblocks;b++) s += scratch[b*128 + j];
  accs[j] = s;
  __syncthreads();
  if (j < 64){
    float m = accs[j]*invN;
    float var = accs[j+64]*invN - m*m;
    stats[j] = m;
    stats[64+j] = rsqrtf(var + BN_EPS);
  }
}

// ---------------- final BN apply: bf16 P -> f32 out ----------------
__global__ __launch_bounds__(256) void bn_apply_k(const u32* __restrict__ P2, const float* __restrict__ stats,
                                                  float4* __restrict__ out, int nq){  // nq = elems/4
  int t = blockIdx.x*256 + threadIdx.x;
  if (t >= nq) return;
  int l = (t*4) & 63;
  u32 v0 = P2[t*2], v1 = P2[t*2+1];
  float4 r;
  r.x = (__uint_as_float((v0 & 0xffffu) << 16) - stats[l+0]) * stats[64+l+0];
  r.y = (__uint_as_float( v0 & 0xffff0000u    ) - stats[l+1]) * stats[64+l+1];
  r.z = (__uint_as_float((v1 & 0xffffu) << 16) - stats[l+2]) * stats[64+l+2];
  r.w = (__uint_as_float( v1 & 0xffff0000u    ) - stats[l+3]) * stats[64+l+3];
  out[t] = r;
}

// ---------------- launcher ----------------
extern "C" void kernel_launch(void* const* d_in, const int* in_sizes, int n_in,
                              void* d_out, int out_size, void* d_ws, size_t ws_size,
                              hipStream_t stream)
{
  const float* x      = (const float*)d_in[0];
  const float* Wl[3]  = {(const float*)d_in[1], (const float*)d_in[7],  (const float*)d_in[13]};
  const float* asl[3] = {(const float*)d_in[2], (const float*)d_in[8],  (const float*)d_in[14]};
  const float* adl[3] = {(const float*)d_in[3], (const float*)d_in[9],  (const float*)d_in[15]};
  const float* bl[3]  = {(const float*)d_in[4], (const float*)d_in[10], (const float*)d_in[16]};
  const int*   el[3]  = {(const int*)d_in[5],   (const int*)d_in[11],   (const int*)d_in[17]};

  const int NS[4]  = {4096, 2048, 1024, 512};
  const int EPB[3] = {32768, 16384, 8192};
  const int LOG2NS[3] = {12, 11, 10};
  const int LOG2E[3]  = {15, 14, 13};
  const int BATCH = 256;

  char* ws = (char*)d_ws;
  size_t off = 0;
  auto alloc = [&](size_t bytes)->char*{
    char* p = ws + off; off += (bytes + 255) & ~(size_t)255; return p;
  };

  u16*   hbuf    = (u16*)alloc((size_t)BATCH*NS[0]*64*2);      // 128 MB, reused per layer
  u16*   Pbuf    = (u16*)alloc((size_t)BATCH*NS[1]*64*2);      //  64 MB, reused per layer
  float* wbuf    = (float*)alloc((size_t)BATCH*EPB[0]*4);      //  32 MB
  float* als     = (float*)alloc((size_t)BATCH*NS[0]*4);       //   4 MB
  float* ald     = (float*)alloc((size_t)BATCH*NS[0]*4);       //   4 MB
  float* scratch = (float*)alloc(256*128*4);                   // 128 KB
  float* stats   = (float*)alloc(384*4);
  int* counts_all = (int*)alloc((size_t)(NS[0]+NS[1]+NS[2])*4);
  int* cursor_all = (int*)alloc((size_t)(NS[0]+NS[1]+NS[2])*4);
  int *counts[3], *cursor[3], *indptr[3], *colv[3], *rowof[3];
  counts[0]=counts_all; counts[1]=counts_all+NS[0]; counts[2]=counts_all+NS[0]+NS[1];
  cursor[0]=cursor_all; cursor[1]=cursor_all+NS[0]; cursor[2]=cursor_all+NS[0]+NS[1];
  for (int i=0;i<3;i++){
    indptr[i] = (int*)alloc((size_t)(NS[i]+1)*4);
    colv[i]   = (int*)alloc((size_t)EPB[i]*4);
    rowof[i]  = (int*)alloc((size_t)EPB[i]*4);
  }
  if (off > ws_size) return;

  // ---- CSR builds ----
  int ctot = NS[0]+NS[1]+NS[2];
  zero_int_k<<<(ctot+255)/256, 256, 0, stream>>>(counts_all, ctot);
  for (int i=0;i<3;i++){
    int nb = EPB[i]/256;
    hist_k<<<nb, 256, 0, stream>>>(el[i] + EPB[i], counts[i], EPB[i]);
    scan_k<<<1, 1024, 0, stream>>>(counts[i], indptr[i], cursor[i], NS[i]);
    scatter_k<<<nb, 256, 0, stream>>>(el[i], el[i] + EPB[i], cursor[i], colv[i], rowof[i], EPB[i]);
  }

  // ---- layers ----
  for (int i=0;i<3;i++){
    int ntot = BATCH*NS[i];
    int npairs = ntot/2;

    if (i==0)
      gemm3_k <<<2048, 256, 0, stream>>>(x, Wl[0], asl[0], adl[0], hbuf, als, ald, ntot);
    else
      gemm64_k<<<2048, 256, 0, stream>>>(Pbuf, Wl[i], asl[i], adl[i], stats + (i-1)*128,
                                         hbuf, als, ald, ntot);

    int ne = BATCH*EPB[i];
    edge_w_k<<<ne/256, 256, 0, stream>>>(colv[i], rowof[i], als, ald, wbuf, LOG2E[i], LOG2NS[i], ne);

    gat_pool_k<<<npairs/4, 256, 0, stream>>>(hbuf, als, ald, bl[i], indptr[i], colv[i], wbuf,
                                             Pbuf, LOG2NS[i], LOG2E[i], npairs, EPB[i]);

    bn_stats_k<<<256, 256, 0, stream>>>(Pbuf, scratch, npairs);
    bn_finish_k<<<1, 128, 0, stream>>>(scratch, stats + i*128, 256, 1.0f/(float)npairs);
  }

  // ---- final BN materialization into d_out ----
  int nq = out_size/4;
  bn_apply_k<<<(nq+255)/256, 256, 0, stream>>>((const u32*)Pbuf, stats + 256, (float4*)d_out, nq);
}

// Round 4
// 1195.600 us; speedup vs baseline: 1.9044x; 1.1344x over previous
//
#include <hip/hip_runtime.h>
#include <stdint.h>

#define NEG_SLOPE 0.2f
#define BN_EPS 1e-5f

typedef unsigned short u16;
typedef unsigned int   u32;
typedef __attribute__((ext_vector_type(2))) float  v2f;
typedef __attribute__((ext_vector_type(4))) float  f32x4;
typedef __attribute__((ext_vector_type(8))) short  short8;

__device__ __forceinline__ float lrelu(float x){ return fmaxf(x, NEG_SLOPE*x); }
__device__ __forceinline__ float bf2f(u16 u){ return __uint_as_float(((u32)u) << 16); }
__device__ __forceinline__ u16 f2bf(float f){           // round-to-nearest-even
  u32 u = __float_as_uint(f);
  return (u16)((u + 0x7fffu + ((u >> 16) & 1u)) >> 16);
}

// ---------------- misc ----------------
__global__ __launch_bounds__(256) void zero_int_k(int* __restrict__ p, int n){
  int t = blockIdx.x*256 + threadIdx.x;
  if (t < n) p[t] = 0;
}

__global__ __launch_bounds__(256) void ell_default_k(u16* __restrict__ es, u16* __restrict__ ed, int n){
  int t = blockIdx.x*256 + threadIdx.x;
  if (t < n){ es[t] = 0xFFFF; ed[t] = 0; }
}

// ---------------- CSR/ELL build (per-graph topology, shared across batch) ----------------
__global__ __launch_bounds__(256) void hist_k(const int* __restrict__ dst, int* __restrict__ counts, int n){
  int t = blockIdx.x*256 + threadIdx.x;
  if (t < n) atomicAdd(&counts[dst[t]], 1);
}

// padded scan: row length = (deg+1 rounded up to x4, incl. self). Writes self slot.
__global__ __launch_bounds__(1024) void scan_pad_k(const int* __restrict__ counts, int* __restrict__ indptr2,
                         int* __restrict__ cursor, u16* __restrict__ ell_src, u16* __restrict__ ell_dst, int n){
  __shared__ int part[1024];
  int tid = threadIdx.x;
  int base = tid*4;
  int v0=0,v1=0,v2=0,v3=0;
  if (base+0<n) v0 = (counts[base+0]+4)&~3;
  if (base+1<n) v1 = (counts[base+1]+4)&~3;
  if (base+2<n) v2 = (counts[base+2]+4)&~3;
  if (base+3<n) v3 = (counts[base+3]+4)&~3;
  part[tid] = v0+v1+v2+v3;
  __syncthreads();
  for (int off=1; off<1024; off<<=1){
    int t2 = (tid>=off)?part[tid-off]:0;
    __syncthreads();
    part[tid] += t2;
    __syncthreads();
  }
  int run = (tid>0)?part[tid-1]:0;
  if (base+0<n){ indptr2[base+0]=run; cursor[base+0]=run+1; ell_src[run]=(u16)(base+0); ell_dst[run]=(u16)(base+0); run+=v0; }
  if (base+1<n){ indptr2[base+1]=run; cursor[base+1]=run+1; ell_src[run]=(u16)(base+1); ell_dst[run]=(u16)(base+1); run+=v1; }
  if (base+2<n){ indptr2[base+2]=run; cursor[base+2]=run+1; ell_src[run]=(u16)(base+2); ell_dst[run]=(u16)(base+2); run+=v2; }
  if (base+3<n){ indptr2[base+3]=run; cursor[base+3]=run+1; ell_src[run]=(u16)(base+3); ell_dst[run]=(u16)(base+3); run+=v3; }
  if (tid==0) indptr2[n] = part[1023];
}

__global__ __launch_bounds__(256) void scatter_k(const int* __restrict__ src, const int* __restrict__ dstl,
                         int* __restrict__ cursor, u16* __restrict__ ell_src, u16* __restrict__ ell_dst, int n){
  int t = blockIdx.x*256 + threadIdx.x;
  if (t < n){
    int dd = dstl[t];
    int p = atomicAdd(&cursor[dd], 1);
    ell_src[p] = (u16)src[t];
    ell_dst[p] = (u16)dd;
  }
}

// ---------------- layer-0 GEMM: x[n,3] @ W0[3,64] -> h bf16, al_s, al_d ----------------
__global__ __launch_bounds__(256) void gemm3_k(const float* __restrict__ x, const float* __restrict__ Wg,
                        const float* __restrict__ asrc, const float* __restrict__ adst,
                        u16* __restrict__ h, float* __restrict__ als, float* __restrict__ ald, int nrows)
{
  const int l = threadIdx.x & 63;
  float W0 = Wg[l], W1 = Wg[64+l], W2 = Wg[128+l];
  const float as_l = asrc[l], ad_l = adst[l];
  int gw = blockIdx.x*4 + (threadIdx.x>>6);
  int stride = gridDim.x*4;
  for (int r = gw; r < nrows; r += stride){
    float x0 = x[(size_t)r*3+0];
    float x1 = x[(size_t)r*3+1];
    float x2 = x[(size_t)r*3+2];
    float acc = fmaf(x0, W0, fmaf(x1, W1, x2*W2));
    h[(size_t)r*64 + l] = f2bf(acc);
    float s = acc*as_l, dsum = acc*ad_l;
    #pragma unroll
    for (int o=32; o>0; o>>=1){ s += __shfl_xor(s,o); dsum += __shfl_xor(dsum,o); }
    if (l==0){ als[r]=s; ald[r]=dsum; }
  }
}

// ---------------- W prep for MFMA GEMM: W' = rstd*W (bf16, B-frag swizzled), c = m*rstd @ W ----------------
// B-frag layout for mfma_f32_16x16x32_bf16: lane l holds B[k = chunk*32 + (l>>4)*8 + j][n = t*16 + (l&15)]
// frag f = t*2+chunk; storage: wswz[(f*64 + l)*8 + j]  (u16 units)
__global__ __launch_bounds__(64) void prep_w_k(const float* __restrict__ W, const float* __restrict__ bn,
                                               u16* __restrict__ wswz, float* __restrict__ cvec){
  int l = threadIdx.x;
  const float* mean = bn;
  const float* rstd = bn + 64;
  #pragma unroll
  for (int f=0; f<8; f++){
    int t = f >> 1, ch = f & 1;
    #pragma unroll
    for (int j=0; j<8; j++){
      int k   = ch*32 + (l>>4)*8 + j;
      int col = t*16 + (l&15);
      wswz[(f*64 + l)*8 + j] = f2bf(rstd[k] * W[k*64 + col]);
    }
  }
  float c = 0.f;
  for (int k=0; k<64; k++) c = fmaf(mean[k]*rstd[k], W[k*64 + l], c);
  cvec[l] = c;
}

// ---------------- layers 1/2 GEMM via MFMA: h = P @ W' - c, plus als/ald ----------------
__global__ __launch_bounds__(256) void gemm64_mfma_k(const u16* __restrict__ Pin, const u16* __restrict__ wswz,
                        const float* __restrict__ cvec, const float* __restrict__ asrc, const float* __restrict__ adst,
                        u16* __restrict__ h, float* __restrict__ als, float* __restrict__ ald, int nblk16)
{
  const int l = threadIdx.x & 63;
  const int q = l >> 4;
  const int c = l & 15;
  short8 B[8];
  const int4* wsw = (const int4*)wswz;
  #pragma unroll
  for (int f=0; f<8; f++){
    int4 v = wsw[f*64 + l];
    B[f] = *(short8*)&v;
  }
  float asl[4], adl[4], cl[4];
  #pragma unroll
  for (int t=0;t<4;t++){ asl[t]=asrc[t*16+c]; adl[t]=adst[t*16+c]; cl[t]=cvec[t*16+c]; }
  int gw = blockIdx.x*4 + (int)(threadIdx.x>>6);
  int stride = gridDim.x*4;
  for (int blk = gw; blk < nblk16; blk += stride){
    size_t rowbase = (size_t)blk*16;
    const int4* arow = (const int4*)(Pin + (rowbase + c)*64);  // A row m = l&15
    int4 a0v = arow[q];       // chunk0: k = q*8+j
    int4 a1v = arow[4+q];     // chunk1: k = 32+q*8+j
    short8 A0 = *(short8*)&a0v, A1 = *(short8*)&a1v;
    f32x4 C0={0.f,0.f,0.f,0.f}, C1=C0, C2=C0, C3=C0;
    C0 = __builtin_amdgcn_mfma_f32_16x16x32_bf16(A0, B[0], C0, 0,0,0);
    C0 = __builtin_amdgcn_mfma_f32_16x16x32_bf16(A1, B[1], C0, 0,0,0);
    C1 = __builtin_amdgcn_mfma_f32_16x16x32_bf16(A0, B[2], C1, 0,0,0);
    C1 = __builtin_amdgcn_mfma_f32_16x16x32_bf16(A1, B[3], C1, 0,0,0);
    C2 = __builtin_amdgcn_mfma_f32_16x16x32_bf16(A0, B[4], C2, 0,0,0);
    C2 = __builtin_amdgcn_mfma_f32_16x16x32_bf16(A1, B[5], C2, 0,0,0);
    C3 = __builtin_amdgcn_mfma_f32_16x16x32_bf16(A0, B[6], C3, 0,0,0);
    C3 = __builtin_amdgcn_mfma_f32_16x16x32_bf16(A1, B[7], C3, 0,0,0);
    // epilogue: C/D layout row = q*4+reg, col (within tile) = c
    float ps0=0.f,ps1=0.f,ps2=0.f,ps3=0.f, pd0=0.f,pd1=0.f,pd2=0.f,pd3=0.f;
    #pragma unroll
    for (int t=0;t<4;t++){
      f32x4 C = (t==0)?C0:(t==1)?C1:(t==2)?C2:C3;
      #pragma unroll
      for (int reg=0;reg<4;reg++){
        float v = C[reg] - cl[t];
        h[(rowbase + q*4 + reg)*64 + t*16 + c] = f2bf(v);
        if (reg==0){ ps0 = fmaf(v, asl[t], ps0); pd0 = fmaf(v, adl[t], pd0); }
        if (reg==1){ ps1 = fmaf(v, asl[t], ps1); pd1 = fmaf(v, adl[t], pd1); }
        if (reg==2){ ps2 = fmaf(v, asl[t], ps2); pd2 = fmaf(v, adl[t], pd2); }
        if (reg==3){ ps3 = fmaf(v, asl[t], ps3); pd3 = fmaf(v, adl[t], pd3); }
      }
    }
    #pragma unroll
    for (int off=1; off<16; off<<=1){
      ps0 += __shfl_xor(ps0, off); pd0 += __shfl_xor(pd0, off);
      ps1 += __shfl_xor(ps1, off); pd1 += __shfl_xor(pd1, off);
      ps2 += __shfl_xor(ps2, off); pd2 += __shfl_xor(pd2, off);
      ps3 += __shfl_xor(ps3, off); pd3 += __shfl_xor(pd3, off);
    }
    if (c == 0){
      size_t r0 = rowbase + q*4;
      als[r0+0]=ps0; als[r0+1]=ps1; als[r0+2]=ps2; als[r0+3]=ps3;
      ald[r0+0]=pd0; ald[r0+1]=pd1; ald[r0+2]=pd2; ald[r0+3]=pd3;
    }
  }
}

// ---------------- per-(graph,slot) attention weight (bf16) ----------------
__global__ __launch_bounds__(256) void wfill_k(const u16* __restrict__ ell_src, const u16* __restrict__ ell_dst,
                        const float* __restrict__ als, const float* __restrict__ ald,
                        u16* __restrict__ ellw, int cap, int log2NS)
{
  int slot = blockIdx.x*256 + threadIdx.x;
  int g = blockIdx.y;
  int s = ell_src[slot];
  u16 w = 0;
  if (s != 0xFFFF){
    int d = ell_dst[slot];
    int base = g << log2NS;
    float e = als[base + s] + ald[base + d];
    w = f2bf(__expf(lrelu(e)));
  }
  ellw[(size_t)g*cap + slot] = w;
}

// ---------------- GAT gather + softmax + bias + relu + pairwise max-pool (ELL) ----------------
// wave per node PAIR; lanes = (half, group, octet); group handles one ELL slot/iter, octet spans 64 feats.
__global__ __launch_bounds__(256) void gat_pool_k(const u16* __restrict__ h, const float* __restrict__ bias,
                      const int* __restrict__ indptr2, const u16* __restrict__ ell_src,
                      const u16* __restrict__ ellw, u16* __restrict__ P,
                      int log2NS, int cap, int npairs)
{
  const int l    = threadIdx.x & 63;
  const int half = l >> 5;
  const int g    = (l >> 3) & 3;
  const int o    = l & 7;
  const int NB   = gridDim.x;
  const int bid  = blockIdx.x;
  const int lb   = (bid & 7) * (NB >> 3) + (bid >> 3);   // XCD swizzle
  const int gw   = lb * 4 + (int)(threadIdx.x >> 6);
  if (gw >= npairs) return;

  const int hbits = log2NS - 1;
  const int b = gw >> hbits;
  const int k = gw & ((1 << hbits) - 1);
  const int d = 2 * k + half;
  const int nmax = (1 << log2NS) - 1;
  const size_t hgbase = ((size_t)(b << log2NS)) << 6;
  const u16* wrow = ellw + (size_t)b * cap;

  const int p0 = indptr2[d];
  const int iters = (indptr2[d+1] - p0) >> 2;

  v2f a01={0.f,0.f}, a23={0.f,0.f}, a45={0.f,0.f}, a67={0.f,0.f};
  float z = 0.f;

  // prologue: slot 0 entry + h row
  int p = p0 + g;
  int   s_cur = ell_src[p];
  u32   wu_cur = wrow[p];
  {
    int sc = (s_cur < nmax) ? s_cur : nmax;
    const u32* hp = (const u32*)(h + hgbase + ((size_t)sc << 6)) + (o << 2);
    // loaded into regs below in first iteration via variables:
    a01.x = 0.f; // placeholder; real loads follow
    (void)hp;
  }
  int sc0 = (s_cur < nmax) ? s_cur : nmax;
  const u32* hp0 = (const u32*)(h + hgbase + ((size_t)sc0 << 6)) + (o << 2);
  u32 r0 = hp0[0], r1 = hp0[1], r2 = hp0[2], r3 = hp0[3];

  for (int it = 0; it < iters; ++it){
    // prefetch next ELL entry (no deps)
    int pn = p0 + (it + 1) * 4 + g;
    int s_n = ell_src[pn];
    u32 wu_n = wrow[pn];
    // consume current
    float w = __uint_as_float(wu_cur << 16);
    z += w;
    v2f w2 = {w, w};
    v2f h01 = { __uint_as_float(r0 << 16), __uint_as_float(r0 & 0xffff0000u) };
    v2f h23 = { __uint_as_float(r1 << 16), __uint_as_float(r1 & 0xffff0000u) };
    v2f h45 = { __uint_as_float(r2 << 16), __uint_as_float(r2 & 0xffff0000u) };
    v2f h67 = { __uint_as_float(r3 << 16), __uint_as_float(r3 & 0xffff0000u) };
    a01 += h01 * w2;
    a23 += h23 * w2;
    a45 += h45 * w2;
    a67 += h67 * w2;
    // prefetch next h row
    int scn = (s_n < nmax) ? s_n : nmax;
    const u32* hpn = (const u32*)(h + hgbase + ((size_t)scn << 6)) + (o << 2);
    r0 = hpn[0]; r1 = hpn[1]; r2 = hpn[2]; r3 = hpn[3];
    s_cur = s_n; wu_cur = wu_n;
  }

  // reduce across the 4 groups within each half
  float q0=a01.x, q1=a01.y, q2=a23.x, q3=a23.y, q4=a45.x, q5=a45.y, q6=a67.x, q7=a67.y;
  #pragma unroll
  for (int off = 8; off <= 16; off <<= 1){
    z  += __shfl_xor(z, off);
    q0 += __shfl_xor(q0, off); q1 += __shfl_xor(q1, off);
    q2 += __shfl_xor(q2, off); q3 += __shfl_xor(q3, off);
    q4 += __shfl_xor(q4, off); q5 += __shfl_xor(q5, off);
    q6 += __shfl_xor(q6, off); q7 += __shfl_xor(q7, off);
  }
  float rz = 1.0f / z;
  const float* bp = bias + (o << 3);
  float4 bA = *(const float4*)(bp);
  float4 bB = *(const float4*)(bp + 4);
  q0 = fmaxf(fmaf(q0, rz, bA.x), 0.f);
  q1 = fmaxf(fmaf(q1, rz, bA.y), 0.f);
  q2 = fmaxf(fmaf(q2, rz, bA.z), 0.f);
  q3 = fmaxf(fmaf(q3, rz, bA.w), 0.f);
  q4 = fmaxf(fmaf(q4, rz, bB.x), 0.f);
  q5 = fmaxf(fmaf(q5, rz, bB.y), 0.f);
  q6 = fmaxf(fmaf(q6, rz, bB.z), 0.f);
  q7 = fmaxf(fmaf(q7, rz, bB.w), 0.f);
  q0 = fmaxf(q0, __shfl_xor(q0, 32));
  q1 = fmaxf(q1, __shfl_xor(q1, 32));
  q2 = fmaxf(q2, __shfl_xor(q2, 32));
  q3 = fmaxf(q3, __shfl_xor(q3, 32));
  q4 = fmaxf(q4, __shfl_xor(q4, 32));
  q5 = fmaxf(q5, __shfl_xor(q5, 32));
  q6 = fmaxf(q6, __shfl_xor(q6, 32));
  q7 = fmaxf(q7, __shfl_xor(q7, 32));
  u32 w0 = (u32)f2bf(q0) | ((u32)f2bf(q1) << 16);
  u32 w1 = (u32)f2bf(q2) | ((u32)f2bf(q3) << 16);
  u32 w2p = (u32)f2bf(q4) | ((u32)f2bf(q5) << 16);
  u32 w3 = (u32)f2bf(q6) | ((u32)f2bf(q7) << 16);
  if (l < 8){
    ((int4*)(P + ((size_t)gw << 6)))[o] = make_int4((int)w0,(int)w1,(int)w2p,(int)w3);
  }
}

// ---------------- BatchNorm stats (2-stage) ----------------
__global__ __launch_bounds__(256) void bn_stats_k(const u16* __restrict__ P, float* __restrict__ scratch, int nrows){
  const int l = threadIdx.x & 63;
  int gw = blockIdx.x*4 + (threadIdx.x>>6);
  int GW = gridDim.x*4;
  float s = 0.f, s2 = 0.f;
  for (int r = gw; r < nrows; r += GW){
    float v = bf2f(P[(size_t)r*64 + l]);
    s += v; s2 = fmaf(v, v, s2);
  }
  __shared__ float ls[256], ls2[256];
  ls[threadIdx.x] = s; ls2[threadIdx.x] = s2;
  __syncthreads();
  if (threadIdx.x < 64){
    float S  = ls[threadIdx.x] + ls[threadIdx.x+64] + ls[threadIdx.x+128] + ls[threadIdx.x+192];
    float S2 = ls2[threadIdx.x] + ls2[threadIdx.x+64] + ls2[threadIdx.x+128] + ls2[threadIdx.x+192];
    scratch[blockIdx.x*128 + threadIdx.x] = S;
    scratch[blockIdx.x*128 + 64 + threadIdx.x] = S2;
  }
}

__global__ __launch_bounds__(128) void bn_finish_k(const float* __restrict__ scratch, float* __restrict__ stats,
                                                   int nblocks, float invN){
  __shared__ float accs[128];
  int j = threadIdx.x;
  float s = 0.f;
  for (int b=0;b<nblocks;b++) s += scratch[b*128 + j];
  accs[j] = s;
  __syncthreads();
  if (j < 64){
    float m = accs[j]*invN;
    float var = accs[j+64]*invN - m*m;
    stats[j] = m;
    stats[64+j] = rsqrtf(var + BN_EPS);
  }
}

// ---------------- final BN apply: bf16 P -> f32 out ----------------
__global__ __launch_bounds__(256) void bn_apply_k(const u32* __restrict__ P2, const float* __restrict__ stats,
                                                  float4* __restrict__ out, int nq){
  int t = blockIdx.x*256 + threadIdx.x;
  if (t >= nq) return;
  int l = (t*4) & 63;
  u32 v0 = P2[t*2], v1 = P2[t*2+1];
  float4 r;
  r.x = (__uint_as_float((v0 & 0xffffu) << 16) - stats[l+0]) * stats[64+l+0];
  r.y = (__uint_as_float( v0 & 0xffff0000u    ) - stats[l+1]) * stats[64+l+1];
  r.z = (__uint_as_float((v1 & 0xffffu) << 16) - stats[l+2]) * stats[64+l+2];
  r.w = (__uint_as_float( v1 & 0xffff0000u    ) - stats[l+3]) * stats[64+l+3];
  out[t] = r;
}

// ---------------- launcher ----------------
extern "C" void kernel_launch(void* const* d_in, const int* in_sizes, int n_in,
                              void* d_out, int out_size, void* d_ws, size_t ws_size,
                              hipStream_t stream)
{
  const float* x      = (const float*)d_in[0];
  const float* Wl[3]  = {(const float*)d_in[1], (const float*)d_in[7],  (const float*)d_in[13]};
  const float* asl[3] = {(const float*)d_in[2], (const float*)d_in[8],  (const float*)d_in[14]};
  const float* adl[3] = {(const float*)d_in[3], (const float*)d_in[9],  (const float*)d_in[15]};
  const float* bl[3]  = {(const float*)d_in[4], (const float*)d_in[10], (const float*)d_in[16]};
  const int*   el[3]  = {(const int*)d_in[5],   (const int*)d_in[11],   (const int*)d_in[17]};

  const int NS[4]  = {4096, 2048, 1024, 512};
  const int EPB[3] = {32768, 16384, 8192};
  const int LOG2NS[3] = {12, 11, 10};
  const int ECAP[3] = {32768+4*4096, 16384+4*2048, 8192+4*1024};  // 49152, 24576, 12288 (x256 each)
  const int BATCH = 256;

  char* ws = (char*)d_ws;
  size_t off = 0;
  auto alloc = [&](size_t bytes)->char*{
    char* p = ws + off; off += (bytes + 255) & ~(size_t)255; return p;
  };

  u16*   hbuf    = (u16*)alloc((size_t)BATCH*NS[0]*64*2);            // 128 MB
  u16*   Pbuf    = (u16*)alloc((size_t)BATCH*NS[1]*64*2);            //  64 MB
  u16*   ellw    = (u16*)alloc(((size_t)BATCH*ECAP[0] + 128)*2);     //  25 MB (sized for L0, reused)
  float* als     = (float*)alloc((size_t)BATCH*NS[0]*4);             //   4 MB
  float* ald     = (float*)alloc((size_t)BATCH*NS[0]*4);             //   4 MB
  float* scratch = (float*)alloc(256*128*4);
  float* stats   = (float*)alloc(384*4);
  u16*   wswz    = (u16*)alloc(8*64*8*2);                            // 8 KB (B-frags)
  float* cvec    = (float*)alloc(64*4);
  int* counts_all = (int*)alloc((size_t)(NS[0]+NS[1]+NS[2])*4);
  int* cursor_all = (int*)alloc((size_t)(NS[0]+NS[1]+NS[2])*4);
  int *counts[3], *cursor[3], *indptr2[3];
  u16 *ell_src[3], *ell_dst[3];
  counts[0]=counts_all; counts[1]=counts_all+NS[0]; counts[2]=counts_all+NS[0]+NS[1];
  cursor[0]=cursor_all; cursor[1]=cursor_all+NS[0]; cursor[2]=cursor_all+NS[0]+NS[1];
  for (int i=0;i<3;i++){
    indptr2[i] = (int*)alloc((size_t)(NS[i]+1)*4);
    ell_src[i] = (u16*)alloc((size_t)(ECAP[i]+16)*2);
    ell_dst[i] = (u16*)alloc((size_t)(ECAP[i]+16)*2);
  }
  if (off > ws_size) return;

  // ---- ELL builds ----
  int ctot = NS[0]+NS[1]+NS[2];
  zero_int_k<<<(ctot+255)/256, 256, 0, stream>>>(counts_all, ctot);
  for (int i=0;i<3;i++){
    int nb = EPB[i]/256;
    hist_k<<<nb, 256, 0, stream>>>(el[i] + EPB[i], counts[i], EPB[i]);
    ell_default_k<<<(ECAP[i]+16+255)/256, 256, 0, stream>>>(ell_src[i], ell_dst[i], ECAP[i]+16);
    scan_pad_k<<<1, 1024, 0, stream>>>(counts[i], indptr2[i], cursor[i], ell_src[i], ell_dst[i], NS[i]);
    scatter_k<<<nb, 256, 0, stream>>>(el[i], el[i] + EPB[i], cursor[i], ell_src[i], ell_dst[i], EPB[i]);
  }

  // ---- layers ----
  for (int i=0;i<3;i++){
    int ntot = BATCH*NS[i];
    int npairs = ntot/2;

    if (i==0){
      gemm3_k<<<2048, 256, 0, stream>>>(x, Wl[0], asl[0], adl[0], hbuf, als, ald, ntot);
    } else {
      prep_w_k<<<1, 64, 0, stream>>>(Wl[i], stats + (i-1)*128, wswz, cvec);
      gemm64_mfma_k<<<2048, 256, 0, stream>>>(Pbuf, wswz, cvec, asl[i], adl[i],
                                              hbuf, als, ald, ntot/16);
    }

    dim3 wgrid(ECAP[i]/256, BATCH);
    wfill_k<<<wgrid, 256, 0, stream>>>(ell_src[i], ell_dst[i], als, ald, ellw, ECAP[i], LOG2NS[i]);

    gat_pool_k<<<npairs/4, 256, 0, stream>>>(hbuf, bl[i], indptr2[i], ell_src[i], ellw,
                                             Pbuf, LOG2NS[i], ECAP[i], npairs);

    bn_stats_k<<<256, 256, 0, stream>>>(Pbuf, scratch, npairs);
    bn_finish_k<<<1, 128, 0, stream>>>(scratch, stats + i*128, 256, 1.0f/(float)npairs);
  }

  // ---- final BN materialization into d_out ----
  int nq = out_size/4;
  bn_apply_k<<<(nq+255)/256, 256, 0, stream>>>((const u32*)Pbuf, stats + 256, (float4*)d_out, nq);
}

// Round 5
// 1077.953 us; speedup vs baseline: 2.1123x; 1.1091x over previous
//
#include <hip/hip_runtime.h>
#include <stdint.h>

#define NEG_SLOPE 0.2f
#define BN_EPS 1e-5f

typedef unsigned short u16;
typedef unsigned int   u32;
typedef __attribute__((ext_vector_type(2))) float  v2f;
typedef __attribute__((ext_vector_type(4))) float  f32x4;
typedef __attribute__((ext_vector_type(8))) short  short8;

__device__ __forceinline__ float lrelu(float x){ return fmaxf(x, NEG_SLOPE*x); }
__device__ __forceinline__ float bf2f(u16 u){ return __uint_as_float(((u32)u) << 16); }
__device__ __forceinline__ u16 f2bf(float f){           // round-to-nearest-even
  u32 u = __float_as_uint(f);
  return (u16)((u + 0x7fffu + ((u >> 16) & 1u)) >> 16);
}

// ---------------- fused build-phase kernels ----------------
__global__ __launch_bounds__(256) void zero_int_k(int* __restrict__ p, int n){
  int t = blockIdx.x*256 + threadIdx.x;
  if (t < n) p[t] = 0;
}

__global__ __launch_bounds__(256) void ell_default_all_k(u16* __restrict__ e0, u16* __restrict__ e1,
                                                         u16* __restrict__ e2, u16* __restrict__ d0,
                                                         u16* __restrict__ d1, u16* __restrict__ d2,
                                                         int n0, int n1, int n2){
  int t = blockIdx.x*256 + threadIdx.x;
  int L = blockIdx.y;
  u16* es = (L==0)?e0:(L==1)?e1:e2;
  u16* ed = (L==0)?d0:(L==1)?d1:d2;
  int n   = (L==0)?n0:(L==1)?n1:n2;
  if (t < n){ es[t] = 0xFFFF; ed[t] = 0; }
}

__global__ __launch_bounds__(256) void hist_all_k(const int* __restrict__ el0, const int* __restrict__ el1,
                                                  const int* __restrict__ el2, int* __restrict__ c0,
                                                  int* __restrict__ c1, int* __restrict__ c2,
                                                  int n0, int n1, int n2){
  int t = blockIdx.x*256 + threadIdx.x;
  int L = blockIdx.y;
  const int* dst = (L==0)?(el0+n0):(L==1)?(el1+n1):(el2+n2);
  int* counts    = (L==0)?c0:(L==1)?c1:c2;
  int n          = (L==0)?n0:(L==1)?n1:n2;
  if (t < n) atomicAdd(&counts[dst[t]], 1);
}

// padded scan per layer (3 blocks): row len = (deg+4)&~3 (>= deg+1), self at slot 0
__global__ __launch_bounds__(1024) void scan_all_k(int* __restrict__ c0, int* __restrict__ c1, int* __restrict__ c2,
                         int* __restrict__ ip0, int* __restrict__ ip1, int* __restrict__ ip2,
                         int* __restrict__ cu0, int* __restrict__ cu1, int* __restrict__ cu2,
                         u16* __restrict__ es0, u16* __restrict__ es1, u16* __restrict__ es2,
                         u16* __restrict__ ed0, u16* __restrict__ ed1, u16* __restrict__ ed2,
                         int n0, int n1, int n2){
  int L = blockIdx.x;
  const int* counts = (L==0)?c0:(L==1)?c1:c2;
  int* indptr2      = (L==0)?ip0:(L==1)?ip1:ip2;
  int* cursor       = (L==0)?cu0:(L==1)?cu1:cu2;
  u16* ell_src      = (L==0)?es0:(L==1)?es1:es2;
  u16* ell_dst      = (L==0)?ed0:(L==1)?ed1:ed2;
  int n             = (L==0)?n0:(L==1)?n1:n2;
  __shared__ int part[1024];
  int tid = threadIdx.x;
  int base = tid*4;
  int v0=0,v1=0,v2=0,v3=0;
  if (base+0<n) v0 = (counts[base+0]+4)&~3;
  if (base+1<n) v1 = (counts[base+1]+4)&~3;
  if (base+2<n) v2 = (counts[base+2]+4)&~3;
  if (base+3<n) v3 = (counts[base+3]+4)&~3;
  part[tid] = v0+v1+v2+v3;
  __syncthreads();
  for (int off=1; off<1024; off<<=1){
    int t2 = (tid>=off)?part[tid-off]:0;
    __syncthreads();
    part[tid] += t2;
    __syncthreads();
  }
  int run = (tid>0)?part[tid-1]:0;
  if (base+0<n){ indptr2[base+0]=run; cursor[base+0]=run+1; ell_src[run]=(u16)(base+0); ell_dst[run]=(u16)(base+0); run+=v0; }
  if (base+1<n){ indptr2[base+1]=run; cursor[base+1]=run+1; ell_src[run]=(u16)(base+1); ell_dst[run]=(u16)(base+1); run+=v1; }
  if (base+2<n){ indptr2[base+2]=run; cursor[base+2]=run+1; ell_src[run]=(u16)(base+2); ell_dst[run]=(u16)(base+2); run+=v2; }
  if (base+3<n){ indptr2[base+3]=run; cursor[base+3]=run+1; ell_src[run]=(u16)(base+3); ell_dst[run]=(u16)(base+3); run+=v3; }
  if (tid==0) indptr2[n] = part[1023];
}

__global__ __launch_bounds__(256) void scatter_all_k(const int* __restrict__ el0, const int* __restrict__ el1,
                         const int* __restrict__ el2, int* __restrict__ cu0, int* __restrict__ cu1,
                         int* __restrict__ cu2, u16* __restrict__ es0, u16* __restrict__ es1,
                         u16* __restrict__ es2, u16* __restrict__ ed0, u16* __restrict__ ed1,
                         u16* __restrict__ ed2, int n0, int n1, int n2){
  int t = blockIdx.x*256 + threadIdx.x;
  int L = blockIdx.y;
  const int* el = (L==0)?el0:(L==1)?el1:el2;
  int* cursor   = (L==0)?cu0:(L==1)?cu1:cu2;
  u16* ell_src  = (L==0)?es0:(L==1)?es1:es2;
  u16* ell_dst  = (L==0)?ed0:(L==1)?ed1:ed2;
  int n         = (L==0)?n0:(L==1)?n1:n2;
  if (t < n){
    int dd = el[n + t];
    int p = atomicAdd(&cursor[dd], 1);
    ell_src[p] = (u16)el[t];
    ell_dst[p] = (u16)dd;
  }
}

// ---------------- layer-0 GEMM: x[n,3] @ W0[3,64] -> h bf16, al_s, al_d ----------------
__global__ __launch_bounds__(256) void gemm3_k(const float* __restrict__ x, const float* __restrict__ Wg,
                        const float* __restrict__ asrc, const float* __restrict__ adst,
                        u16* __restrict__ h, float* __restrict__ als, float* __restrict__ ald, int nrows)
{
  const int l = threadIdx.x & 63;
  float W0 = Wg[l], W1 = Wg[64+l], W2 = Wg[128+l];
  const float as_l = asrc[l], ad_l = adst[l];
  int gw = blockIdx.x*4 + (threadIdx.x>>6);
  int stride = gridDim.x*4;
  for (int r = gw; r < nrows; r += stride){
    float x0 = x[(size_t)r*3+0];
    float x1 = x[(size_t)r*3+1];
    float x2 = x[(size_t)r*3+2];
    float acc = fmaf(x0, W0, fmaf(x1, W1, x2*W2));
    h[(size_t)r*64 + l] = f2bf(acc);
    float s = acc*as_l, dsum = acc*ad_l;
    #pragma unroll
    for (int o=32; o>0; o>>=1){ s += __shfl_xor(s,o); dsum += __shfl_xor(dsum,o); }
    if (l==0){ als[r]=s; ald[r]=dsum; }
  }
}

// ---------------- W prep for MFMA GEMM ----------------
__global__ __launch_bounds__(64) void prep_w_k(const float* __restrict__ W, const float* __restrict__ bn,
                                               u16* __restrict__ wswz, float* __restrict__ cvec){
  int l = threadIdx.x;
  const float* mean = bn;
  const float* rstd = bn + 64;
  #pragma unroll
  for (int f=0; f<8; f++){
    int t = f >> 1, ch = f & 1;
    #pragma unroll
    for (int j=0; j<8; j++){
      int k   = ch*32 + (l>>4)*8 + j;
      int col = t*16 + (l&15);
      wswz[(f*64 + l)*8 + j] = f2bf(rstd[k] * W[k*64 + col]);
    }
  }
  float c = 0.f;
  for (int k=0; k<64; k++) c = fmaf(mean[k]*rstd[k], W[k*64 + l], c);
  cvec[l] = c;
}

// ---------------- layers 1/2 GEMM via MFMA: h = P @ W' - c, plus als/ald ----------------
__global__ __launch_bounds__(256) void gemm64_mfma_k(const u16* __restrict__ Pin, const u16* __restrict__ wswz,
                        const float* __restrict__ cvec, const float* __restrict__ asrc, const float* __restrict__ adst,
                        u16* __restrict__ h, float* __restrict__ als, float* __restrict__ ald, int nblk16)
{
  const int l = threadIdx.x & 63;
  const int q = l >> 4;
  const int c = l & 15;
  short8 B[8];
  const int4* wsw = (const int4*)wswz;
  #pragma unroll
  for (int f=0; f<8; f++){
    int4 v = wsw[f*64 + l];
    B[f] = *(short8*)&v;
  }
  float asl[4], adl[4], cl[4];
  #pragma unroll
  for (int t=0;t<4;t++){ asl[t]=asrc[t*16+c]; adl[t]=adst[t*16+c]; cl[t]=cvec[t*16+c]; }
  int gw = blockIdx.x*4 + (int)(threadIdx.x>>6);
  int stride = gridDim.x*4;
  for (int blk = gw; blk < nblk16; blk += stride){
    size_t rowbase = (size_t)blk*16;
    const int4* arow = (const int4*)(Pin + (rowbase + c)*64);
    int4 a0v = arow[q];
    int4 a1v = arow[4+q];
    short8 A0 = *(short8*)&a0v, A1 = *(short8*)&a1v;
    f32x4 C0={0.f,0.f,0.f,0.f}, C1=C0, C2=C0, C3=C0;
    C0 = __builtin_amdgcn_mfma_f32_16x16x32_bf16(A0, B[0], C0, 0,0,0);
    C0 = __builtin_amdgcn_mfma_f32_16x16x32_bf16(A1, B[1], C0, 0,0,0);
    C1 = __builtin_amdgcn_mfma_f32_16x16x32_bf16(A0, B[2], C1, 0,0,0);
    C1 = __builtin_amdgcn_mfma_f32_16x16x32_bf16(A1, B[3], C1, 0,0,0);
    C2 = __builtin_amdgcn_mfma_f32_16x16x32_bf16(A0, B[4], C2, 0,0,0);
    C2 = __builtin_amdgcn_mfma_f32_16x16x32_bf16(A1, B[5], C2, 0,0,0);
    C3 = __builtin_amdgcn_mfma_f32_16x16x32_bf16(A0, B[6], C3, 0,0,0);
    C3 = __builtin_amdgcn_mfma_f32_16x16x32_bf16(A1, B[7], C3, 0,0,0);
    float ps0=0.f,ps1=0.f,ps2=0.f,ps3=0.f, pd0=0.f,pd1=0.f,pd2=0.f,pd3=0.f;
    #pragma unroll
    for (int t=0;t<4;t++){
      f32x4 C = (t==0)?C0:(t==1)?C1:(t==2)?C2:C3;
      #pragma unroll
      for (int reg=0;reg<4;reg++){
        float v = C[reg] - cl[t];
        h[(rowbase + q*4 + reg)*64 + t*16 + c] = f2bf(v);
        if (reg==0){ ps0 = fmaf(v, asl[t], ps0); pd0 = fmaf(v, adl[t], pd0); }
        if (reg==1){ ps1 = fmaf(v, asl[t], ps1); pd1 = fmaf(v, adl[t], pd1); }
        if (reg==2){ ps2 = fmaf(v, asl[t], ps2); pd2 = fmaf(v, adl[t], pd2); }
        if (reg==3){ ps3 = fmaf(v, asl[t], ps3); pd3 = fmaf(v, adl[t], pd3); }
      }
    }
    #pragma unroll
    for (int off=1; off<16; off<<=1){
      ps0 += __shfl_xor(ps0, off); pd0 += __shfl_xor(pd0, off);
      ps1 += __shfl_xor(ps1, off); pd1 += __shfl_xor(pd1, off);
      ps2 += __shfl_xor(ps2, off); pd2 += __shfl_xor(pd2, off);
      ps3 += __shfl_xor(ps3, off); pd3 += __shfl_xor(pd3, off);
    }
    if (c == 0){
      size_t r0 = rowbase + q*4;
      als[r0+0]=ps0; als[r0+1]=ps1; als[r0+2]=ps2; als[r0+3]=ps3;
      ald[r0+0]=pd0; ald[r0+1]=pd1; ald[r0+2]=pd2; ald[r0+3]=pd3;
    }
  }
}

// ---------------- per-(graph,slot) packed entry: src | (bf16 w << 16) ----------------
__global__ __launch_bounds__(256) void wfill_k(const u16* __restrict__ ell_src, const u16* __restrict__ ell_dst,
                        const float* __restrict__ als, const float* __restrict__ ald,
                        u32* __restrict__ epack, int cap, int log2NS)
{
  int slot = blockIdx.x*256 + threadIdx.x;
  int g = blockIdx.y;
  int s = ell_src[slot];
  u32 w = 0;
  if (s != 0xFFFF){
    int d = ell_dst[slot];
    int base = g << log2NS;
    float e = als[base + s] + ald[base + d];
    w = (u32)f2bf(__expf(lrelu(e))) << 16;
  }
  epack[(size_t)g*cap + slot] = (u32)(s & 0xFFFF) | w;
}

// ---------------- GAT gather + softmax + bias + relu + pairwise max-pool ----------------
// wave = 8 groups x 8 lanes; group g owns node (wv*8+g); no cross-group sum reduction.
__global__ __launch_bounds__(256) void gat_pool_k(const u16* __restrict__ h, const float* __restrict__ bias,
                      const int* __restrict__ indptr2, const int* __restrict__ counts,
                      const u32* __restrict__ epack, u16* __restrict__ P,
                      int log2NS, int cap, int nwaves)
{
  const int l = threadIdx.x & 63;
  const int g = l >> 3;
  const int o = l & 7;
  const int NB  = gridDim.x;
  const int bid = blockIdx.x;
  const int lb  = (bid & 7) * (NB >> 3) + (bid >> 3);   // XCD swizzle
  const int wv  = lb * 4 + (int)(threadIdx.x >> 6);
  if (wv >= nwaves) return;

  const int wbits = log2NS - 3;
  const int b = wv >> wbits;
  const int d = ((wv & ((1 << wbits) - 1)) << 3) + g;    // this group's node
  const u32* hb = (const u32*)(h + ((((size_t)b << log2NS)) << 6)) + (o << 2);
  const u32* erow = epack + (size_t)b * cap;

  const int p0  = indptr2[d];
  const int cnt = counts[d] + 1;                          // deg + self

  // hoisted per-lane constants
  const float* bp = bias + (o << 3);
  float4 bA = *(const float4*)(bp);
  float4 bB = *(const float4*)(bp + 4);

  v2f a01={0.f,0.f}, a23={0.f,0.f}, a45={0.f,0.f}, a67={0.f,0.f};
  float z = 0.f;

  u32 e = erow[p0];
  for (int it = 0; it < cnt; ++it){
    u32 e_n = erow[p0 + it + 1];                          // prefetch (padded slots exist)
    int s = e & 0xffff;
    float w = __uint_as_float(e & 0xffff0000u);
    const u32* hp = hb + ((size_t)s << 5);                // s*64 elems = s*32 u32
    u32 r0 = hp[0], r1 = hp[1], r2 = hp[2], r3 = hp[3];
    z += w;
    v2f w2 = {w, w};
    a01 += (v2f){ __uint_as_float(r0 << 16), __uint_as_float(r0 & 0xffff0000u) } * w2;
    a23 += (v2f){ __uint_as_float(r1 << 16), __uint_as_float(r1 & 0xffff0000u) } * w2;
    a45 += (v2f){ __uint_as_float(r2 << 16), __uint_as_float(r2 & 0xffff0000u) } * w2;
    a67 += (v2f){ __uint_as_float(r3 << 16), __uint_as_float(r3 & 0xffff0000u) } * w2;
    e = e_n;
  }

  float rz = __builtin_amdgcn_rcpf(z);
  float q0 = fmaxf(fmaf(a01.x, rz, bA.x), 0.f);
  float q1 = fmaxf(fmaf(a01.y, rz, bA.y), 0.f);
  float q2 = fmaxf(fmaf(a23.x, rz, bA.z), 0.f);
  float q3 = fmaxf(fmaf(a23.y, rz, bA.w), 0.f);
  float q4 = fmaxf(fmaf(a45.x, rz, bB.x), 0.f);
  float q5 = fmaxf(fmaf(a45.y, rz, bB.y), 0.f);
  float q6 = fmaxf(fmaf(a67.x, rz, bB.z), 0.f);
  float q7 = fmaxf(fmaf(a67.y, rz, bB.w), 0.f);
  // pool pair: groups g and g^1 hold the two nodes of a cluster
  q0 = fmaxf(q0, __shfl_xor(q0, 8));
  q1 = fmaxf(q1, __shfl_xor(q1, 8));
  q2 = fmaxf(q2, __shfl_xor(q2, 8));
  q3 = fmaxf(q3, __shfl_xor(q3, 8));
  q4 = fmaxf(q4, __shfl_xor(q4, 8));
  q5 = fmaxf(q5, __shfl_xor(q5, 8));
  q6 = fmaxf(q6, __shfl_xor(q6, 8));
  q7 = fmaxf(q7, __shfl_xor(q7, 8));
  if ((g & 1) == 0){
    u32 w0 = (u32)f2bf(q0) | ((u32)f2bf(q1) << 16);
    u32 w1 = (u32)f2bf(q2) | ((u32)f2bf(q3) << 16);
    u32 w2p = (u32)f2bf(q4) | ((u32)f2bf(q5) << 16);
    u32 w3 = (u32)f2bf(q6) | ((u32)f2bf(q7) << 16);
    size_t prow = (size_t)wv*4 + (g >> 1);
    ((int4*)(P + (prow << 6)))[o] = make_int4((int)w0,(int)w1,(int)w2p,(int)w3);
  }
}

// ---------------- BatchNorm stats (2-stage) ----------------
__global__ __launch_bounds__(256) void bn_stats_k(const u16* __restrict__ P, float* __restrict__ scratch, int nrows){
  const int l = threadIdx.x & 63;
  int gw = blockIdx.x*4 + (threadIdx.x>>6);
  int GW = gridDim.x*4;
  float s = 0.f, s2 = 0.f;
  for (int r = gw; r < nrows; r += GW){
    float v = bf2f(P[(size_t)r*64 + l]);
    s += v; s2 = fmaf(v, v, s2);
  }
  __shared__ float ls[256], ls2[256];
  ls[threadIdx.x] = s; ls2[threadIdx.x] = s2;
  __syncthreads();
  if (threadIdx.x < 64){
    float S  = ls[threadIdx.x] + ls[threadIdx.x+64] + ls[threadIdx.x+128] + ls[threadIdx.x+192];
    float S2 = ls2[threadIdx.x] + ls2[threadIdx.x+64] + ls2[threadIdx.x+128] + ls2[threadIdx.x+192];
    scratch[blockIdx.x*128 + threadIdx.x] = S;
    scratch[blockIdx.x*128 + 64 + threadIdx.x] = S2;
  }
}

__global__ __launch_bounds__(128) void bn_finish_k(const float* __restrict__ scratch, float* __restrict__ stats,
                                                   int nblocks, float invN){
  __shared__ float accs[128];
  int j = threadIdx.x;
  float s = 0.f;
  for (int b=0;b<nblocks;b++) s += scratch[b*128 + j];
  accs[j] = s;
  __syncthreads();
  if (j < 64){
    float m = accs[j]*invN;
    float var = accs[j+64]*invN - m*m;
    stats[j] = m;
    stats[64+j] = rsqrtf(var + BN_EPS);
  }
}

// ---------------- final BN apply: bf16 P -> f32 out ----------------
__global__ __launch_bounds__(256) void bn_apply_k(const u32* __restrict__ P2, const float* __restrict__ stats,
                                                  float4* __restrict__ out, int nq){
  int t = blockIdx.x*256 + threadIdx.x;
  if (t >= nq) return;
  int l = (t*4) & 63;
  u32 v0 = P2[t*2], v1 = P2[t*2+1];
  float4 r;
  r.x = (__uint_as_float((v0 & 0xffffu) << 16) - stats[l+0]) * stats[64+l+0];
  r.y = (__uint_as_float( v0 & 0xffff0000u    ) - stats[l+1]) * stats[64+l+1];
  r.z = (__uint_as_float((v1 & 0xffffu) << 16) - stats[l+2]) * stats[64+l+2];
  r.w = (__uint_as_float( v1 & 0xffff0000u    ) - stats[l+3]) * stats[64+l+3];
  out[t] = r;
}

// ---------------- launcher ----------------
extern "C" void kernel_launch(void* const* d_in, const int* in_sizes, int n_in,
                              void* d_out, int out_size, void* d_ws, size_t ws_size,
                              hipStream_t stream)
{
  const float* x      = (const float*)d_in[0];
  const float* Wl[3]  = {(const float*)d_in[1], (const float*)d_in[7],  (const float*)d_in[13]};
  const float* asl[3] = {(const float*)d_in[2], (const float*)d_in[8],  (const float*)d_in[14]};
  const float* adl[3] = {(const float*)d_in[3], (const float*)d_in[9],  (const float*)d_in[15]};
  const float* bl[3]  = {(const float*)d_in[4], (const float*)d_in[10], (const float*)d_in[16]};
  const int*   el[3]  = {(const int*)d_in[5],   (const int*)d_in[11],   (const int*)d_in[17]};

  const int NS[4]  = {4096, 2048, 1024, 512};
  const int EPB[3] = {32768, 16384, 8192};
  const int LOG2NS[3] = {12, 11, 10};
  const int ECAP[3] = {32768+4*4096, 16384+4*2048, 8192+4*1024};  // 49152, 24576, 12288
  const int BATCH = 256;

  char* ws = (char*)d_ws;
  size_t off = 0;
  auto alloc = [&](size_t bytes)->char*{
    char* p = ws + off; off += (bytes + 255) & ~(size_t)255; return p;
  };

  u16*   hbuf    = (u16*)alloc((size_t)BATCH*NS[0]*64*2);            // 128 MB
  u16*   Pbuf    = (u16*)alloc((size_t)BATCH*NS[1]*64*2);            //  64 MB
  u32*   epack   = (u32*)alloc(((size_t)BATCH*ECAP[0] + 64)*4);      //  50 MB
  float* als     = (float*)alloc((size_t)BATCH*NS[0]*4);             //   4 MB
  float* ald     = (float*)alloc((size_t)BATCH*NS[0]*4);             //   4 MB
  float* scratch = (float*)alloc(256*128*4);
  float* stats   = (float*)alloc(384*4);
  u16*   wswz    = (u16*)alloc(8*64*8*2);
  float* cvec    = (float*)alloc(64*4);
  int* counts_all = (int*)alloc((size_t)(NS[0]+NS[1]+NS[2])*4);
  int* cursor_all = (int*)alloc((size_t)(NS[0]+NS[1]+NS[2])*4);
  int *counts[3], *cursor[3], *indptr2[3];
  u16 *ell_src[3], *ell_dst[3];
  counts[0]=counts_all; counts[1]=counts_all+NS[0]; counts[2]=counts_all+NS[0]+NS[1];
  cursor[0]=cursor_all; cursor[1]=cursor_all+NS[0]; cursor[2]=cursor_all+NS[0]+NS[1];
  for (int i=0;i<3;i++){
    indptr2[i] = (int*)alloc((size_t)(NS[i]+1)*4);
    ell_src[i] = (u16*)alloc((size_t)(ECAP[i]+16)*2);
    ell_dst[i] = (u16*)alloc((size_t)(ECAP[i]+16)*2);
  }
  if (off > ws_size) return;

  // ---- fused ELL build ----
  int ctot = NS[0]+NS[1]+NS[2];
  zero_int_k<<<(ctot+255)/256, 256, 0, stream>>>(counts_all, ctot);
  {
    dim3 gdef((ECAP[0]+16+255)/256, 3);
    ell_default_all_k<<<gdef, 256, 0, stream>>>(ell_src[0], ell_src[1], ell_src[2],
                                                ell_dst[0], ell_dst[1], ell_dst[2],
                                                ECAP[0]+16, ECAP[1]+16, ECAP[2]+16);
    dim3 ghist(EPB[0]/256, 3);
    hist_all_k<<<ghist, 256, 0, stream>>>(el[0], el[1], el[2], counts[0], counts[1], counts[2],
                                          EPB[0], EPB[1], EPB[2]);
    scan_all_k<<<3, 1024, 0, stream>>>(counts[0], counts[1], counts[2],
                                       indptr2[0], indptr2[1], indptr2[2],
                                       cursor[0], cursor[1], cursor[2],
                                       ell_src[0], ell_src[1], ell_src[2],
                                       ell_dst[0], ell_dst[1], ell_dst[2],
                                       NS[0], NS[1], NS[2]);
    scatter_all_k<<<ghist, 256, 0, stream>>>(el[0], el[1], el[2],
                                             cursor[0], cursor[1], cursor[2],
                                             ell_src[0], ell_src[1], ell_src[2],
                                             ell_dst[0], ell_dst[1], ell_dst[2],
                                             EPB[0], EPB[1], EPB[2]);
  }

  // ---- layers ----
  for (int i=0;i<3;i++){
    int ntot = BATCH*NS[i];

    if (i==0){
      gemm3_k<<<2048, 256, 0, stream>>>(x, Wl[0], asl[0], adl[0], hbuf, als, ald, ntot);
    } else {
      prep_w_k<<<1, 64, 0, stream>>>(Wl[i], stats + (i-1)*128, wswz, cvec);
      gemm64_mfma_k<<<2048, 256, 0, stream>>>(Pbuf, wswz, cvec, asl[i], adl[i],
                                              hbuf, als, ald, ntot/16);
    }

    dim3 wgrid(ECAP[i]/256, BATCH);
    wfill_k<<<wgrid, 256, 0, stream>>>(ell_src[i], ell_dst[i], als, ald, epack, ECAP[i], LOG2NS[i]);

    int nwaves = ntot/8;
    gat_pool_k<<<nwaves/4, 256, 0, stream>>>(hbuf, bl[i], indptr2[i], counts[i], epack,
                                             Pbuf, LOG2NS[i], ECAP[i], nwaves);

    bn_stats_k<<<256, 256, 0, stream>>>(Pbuf, scratch, ntot/2);
    bn_finish_k<<<1, 128, 0, stream>>>(scratch, stats + i*128, 256, 1.0f/(float)(ntot/2));
  }

  // ---- final BN materialization into d_out ----
  int nq = out_size/4;
  bn_apply_k<<<(nq+255)/256, 256, 0, stream>>>((const u32*)Pbuf, stats + 256, (float4*)d_out, nq);
}

// Round 6
// 947.872 us; speedup vs baseline: 2.4022x; 1.1372x over previous
//
#include <hip/hip_runtime.h>
#include <stdint.h>

#define NEG_SLOPE 0.2f
#define BN_EPS 1e-5f

typedef unsigned short u16;
typedef unsigned int   u32;
typedef __attribute__((ext_vector_type(2))) float  v2f;
typedef __attribute__((ext_vector_type(4))) float  f32x4;
typedef __attribute__((ext_vector_type(8))) short  short8;

__device__ __forceinline__ float lrelu(float x){ return fmaxf(x, NEG_SLOPE*x); }
__device__ __forceinline__ float bf2f(u16 u){ return __uint_as_float(((u32)u) << 16); }
__device__ __forceinline__ u16 f2bf(float f){           // round-to-nearest-even
  u32 u = __float_as_uint(f);
  return (u16)((u + 0x7fffu + ((u >> 16) & 1u)) >> 16);
}

// ---------------- fused build-phase kernels ----------------
__global__ __launch_bounds__(256) void zero_int_k(int* __restrict__ p, int n){
  int t = blockIdx.x*256 + threadIdx.x;
  if (t < n) p[t] = 0;
}

__global__ __launch_bounds__(256) void ell_default_all_k(u16* __restrict__ e0, u16* __restrict__ e1,
                                                         u16* __restrict__ e2, u16* __restrict__ d0,
                                                         u16* __restrict__ d1, u16* __restrict__ d2,
                                                         int n0, int n1, int n2){
  int t = blockIdx.x*256 + threadIdx.x;
  int L = blockIdx.y;
  u16* es = (L==0)?e0:(L==1)?e1:e2;
  u16* ed = (L==0)?d0:(L==1)?d1:d2;
  int n   = (L==0)?n0:(L==1)?n1:n2;
  if (t < n){ es[t] = 0xFFFF; ed[t] = 0; }
}

__global__ __launch_bounds__(256) void hist_all_k(const int* __restrict__ el0, const int* __restrict__ el1,
                                                  const int* __restrict__ el2, int* __restrict__ c0,
                                                  int* __restrict__ c1, int* __restrict__ c2,
                                                  int n0, int n1, int n2){
  int t = blockIdx.x*256 + threadIdx.x;
  int L = blockIdx.y;
  const int* dst = (L==0)?(el0+n0):(L==1)?(el1+n1):(el2+n2);
  int* counts    = (L==0)?c0:(L==1)?c1:c2;
  int n          = (L==0)?n0:(L==1)?n1:n2;
  if (t < n) atomicAdd(&counts[dst[t]], 1);
}

// padded scan per layer (3 blocks): row len = (deg+4)&~3 (>= deg+1), self at slot 0
__global__ __launch_bounds__(1024) void scan_all_k(int* __restrict__ c0, int* __restrict__ c1, int* __restrict__ c2,
                         int* __restrict__ ip0, int* __restrict__ ip1, int* __restrict__ ip2,
                         int* __restrict__ cu0, int* __restrict__ cu1, int* __restrict__ cu2,
                         u16* __restrict__ es0, u16* __restrict__ es1, u16* __restrict__ es2,
                         u16* __restrict__ ed0, u16* __restrict__ ed1, u16* __restrict__ ed2,
                         int n0, int n1, int n2){
  int L = blockIdx.x;
  const int* counts = (L==0)?c0:(L==1)?c1:c2;
  int* indptr2      = (L==0)?ip0:(L==1)?ip1:ip2;
  int* cursor       = (L==0)?cu0:(L==1)?cu1:cu2;
  u16* ell_src      = (L==0)?es0:(L==1)?es1:es2;
  u16* ell_dst      = (L==0)?ed0:(L==1)?ed1:ed2;
  int n             = (L==0)?n0:(L==1)?n1:n2;
  __shared__ int part[1024];
  int tid = threadIdx.x;
  int base = tid*4;
  int v0=0,v1=0,v2=0,v3=0;
  if (base+0<n) v0 = (counts[base+0]+4)&~3;
  if (base+1<n) v1 = (counts[base+1]+4)&~3;
  if (base+2<n) v2 = (counts[base+2]+4)&~3;
  if (base+3<n) v3 = (counts[base+3]+4)&~3;
  part[tid] = v0+v1+v2+v3;
  __syncthreads();
  for (int off=1; off<1024; off<<=1){
    int t2 = (tid>=off)?part[tid-off]:0;
    __syncthreads();
    part[tid] += t2;
    __syncthreads();
  }
  int run = (tid>0)?part[tid-1]:0;
  if (base+0<n){ indptr2[base+0]=run; cursor[base+0]=run+1; ell_src[run]=(u16)(base+0); ell_dst[run]=(u16)(base+0); run+=v0; }
  if (base+1<n){ indptr2[base+1]=run; cursor[base+1]=run+1; ell_src[run]=(u16)(base+1); ell_dst[run]=(u16)(base+1); run+=v1; }
  if (base+2<n){ indptr2[base+2]=run; cursor[base+2]=run+1; ell_src[run]=(u16)(base+2); ell_dst[run]=(u16)(base+2); run+=v2; }
  if (base+3<n){ indptr2[base+3]=run; cursor[base+3]=run+1; ell_src[run]=(u16)(base+3); ell_dst[run]=(u16)(base+3); run+=v3; }
  if (tid==0) indptr2[n] = part[1023];
}

__global__ __launch_bounds__(256) void scatter_all_k(const int* __restrict__ el0, const int* __restrict__ el1,
                         const int* __restrict__ el2, int* __restrict__ cu0, int* __restrict__ cu1,
                         int* __restrict__ cu2, u16* __restrict__ es0, u16* __restrict__ es1,
                         u16* __restrict__ es2, u16* __restrict__ ed0, u16* __restrict__ ed1,
                         u16* __restrict__ ed2, int n0, int n1, int n2){
  int t = blockIdx.x*256 + threadIdx.x;
  int L = blockIdx.y;
  const int* el = (L==0)?el0:(L==1)?el1:el2;
  int* cursor   = (L==0)?cu0:(L==1)?cu1:cu2;
  u16* ell_src  = (L==0)?es0:(L==1)?es1:es2;
  u16* ell_dst  = (L==0)?ed0:(L==1)?ed1:ed2;
  int n         = (L==0)?n0:(L==1)?n1:n2;
  if (t < n){
    int dd = el[n + t];
    int p = atomicAdd(&cursor[dd], 1);
    ell_src[p] = (u16)el[t];
    ell_dst[p] = (u16)dd;
  }
}

// ---------------- layer-0 GEMM: x[n,3] @ W0[3,64] -> h bf16, al_s, al_d ----------------
// 8 lanes per row x 8 rows per wave; lane = (row g, feature-octet o); int4 coalesced stores.
__global__ __launch_bounds__(256) void gemm3_k(const float* __restrict__ x, const float* __restrict__ Wg,
                        const float* __restrict__ asrc, const float* __restrict__ adst,
                        u16* __restrict__ h, float* __restrict__ als, float* __restrict__ ald, int nrows8)
{
  const int l = threadIdx.x & 63;
  const int g = l >> 3;     // row within 8-row tile
  const int o = l & 7;      // feature octet
  float W0[8], W1[8], W2[8], as8[8], ad8[8];
  #pragma unroll
  for (int j=0;j<8;j++){
    W0[j] = Wg[      o*8 + j];
    W1[j] = Wg[ 64 + o*8 + j];
    W2[j] = Wg[128 + o*8 + j];
    as8[j] = asrc[o*8 + j];
    ad8[j] = adst[o*8 + j];
  }
  int wv = blockIdx.x*4 + (int)(threadIdx.x>>6);
  int stride = gridDim.x*4;
  for (int blk = wv; blk < nrows8; blk += stride){
    int r = blk*8 + g;
    float x0 = x[(size_t)r*3+0];
    float x1 = x[(size_t)r*3+1];
    float x2 = x[(size_t)r*3+2];
    float s = 0.f, dsum = 0.f;
    u32 pk[4];
    #pragma unroll
    for (int j=0;j<8;j+=2){
      float a0 = fmaf(x0, W0[j],   fmaf(x1, W1[j],   x2*W2[j]));
      float a1 = fmaf(x0, W0[j+1], fmaf(x1, W1[j+1], x2*W2[j+1]));
      s    = fmaf(a0, as8[j], fmaf(a1, as8[j+1], s));
      dsum = fmaf(a0, ad8[j], fmaf(a1, ad8[j+1], dsum));
      pk[j>>1] = (u32)f2bf(a0) | ((u32)f2bf(a1) << 16);
    }
    ((int4*)(h + ((size_t)r << 6)))[o] = make_int4((int)pk[0],(int)pk[1],(int)pk[2],(int)pk[3]);
    #pragma unroll
    for (int off=1; off<8; off<<=1){
      s    += __shfl_xor(s, off);
      dsum += __shfl_xor(dsum, off);
    }
    if (o == 0){ als[r] = s; ald[r] = dsum; }
  }
}

// ---------------- W prep for MFMA GEMM ----------------
__global__ __launch_bounds__(64) void prep_w_k(const float* __restrict__ W, const float* __restrict__ bn,
                                               u16* __restrict__ wswz, float* __restrict__ cvec){
  int l = threadIdx.x;
  const float* mean = bn;
  const float* rstd = bn + 64;
  #pragma unroll
  for (int f=0; f<8; f++){
    int t = f >> 1, ch = f & 1;
    #pragma unroll
    for (int j=0; j<8; j++){
      int k   = ch*32 + (l>>4)*8 + j;
      int col = t*16 + (l&15);
      wswz[(f*64 + l)*8 + j] = f2bf(rstd[k] * W[k*64 + col]);
    }
  }
  float c = 0.f;
  for (int k=0; k<64; k++) c = fmaf(mean[k]*rstd[k], W[k*64 + l], c);
  cvec[l] = c;
}

// ---------------- layers 1/2 GEMM via MFMA: h = P @ W' - c, plus als/ald ----------------
__global__ __launch_bounds__(256) void gemm64_mfma_k(const u16* __restrict__ Pin, const u16* __restrict__ wswz,
                        const float* __restrict__ cvec, const float* __restrict__ asrc, const float* __restrict__ adst,
                        u16* __restrict__ h, float* __restrict__ als, float* __restrict__ ald, int nblk16)
{
  const int l = threadIdx.x & 63;
  const int q = l >> 4;
  const int c = l & 15;
  short8 B[8];
  const int4* wsw = (const int4*)wswz;
  #pragma unroll
  for (int f=0; f<8; f++){
    int4 v = wsw[f*64 + l];
    B[f] = *(short8*)&v;
  }
  float asl[4], adl[4], cl[4];
  #pragma unroll
  for (int t=0;t<4;t++){ asl[t]=asrc[t*16+c]; adl[t]=adst[t*16+c]; cl[t]=cvec[t*16+c]; }
  int gw = blockIdx.x*4 + (int)(threadIdx.x>>6);
  int stride = gridDim.x*4;
  for (int blk = gw; blk < nblk16; blk += stride){
    size_t rowbase = (size_t)blk*16;
    const int4* arow = (const int4*)(Pin + (rowbase + c)*64);
    int4 a0v = arow[q];
    int4 a1v = arow[4+q];
    short8 A0 = *(short8*)&a0v, A1 = *(short8*)&a1v;
    f32x4 C0={0.f,0.f,0.f,0.f}, C1=C0, C2=C0, C3=C0;
    C0 = __builtin_amdgcn_mfma_f32_16x16x32_bf16(A0, B[0], C0, 0,0,0);
    C0 = __builtin_amdgcn_mfma_f32_16x16x32_bf16(A1, B[1], C0, 0,0,0);
    C1 = __builtin_amdgcn_mfma_f32_16x16x32_bf16(A0, B[2], C1, 0,0,0);
    C1 = __builtin_amdgcn_mfma_f32_16x16x32_bf16(A1, B[3], C1, 0,0,0);
    C2 = __builtin_amdgcn_mfma_f32_16x16x32_bf16(A0, B[4], C2, 0,0,0);
    C2 = __builtin_amdgcn_mfma_f32_16x16x32_bf16(A1, B[5], C2, 0,0,0);
    C3 = __builtin_amdgcn_mfma_f32_16x16x32_bf16(A0, B[6], C3, 0,0,0);
    C3 = __builtin_amdgcn_mfma_f32_16x16x32_bf16(A1, B[7], C3, 0,0,0);
    float ps0=0.f,ps1=0.f,ps2=0.f,ps3=0.f, pd0=0.f,pd1=0.f,pd2=0.f,pd3=0.f;
    #pragma unroll
    for (int t=0;t<4;t++){
      f32x4 C = (t==0)?C0:(t==1)?C1:(t==2)?C2:C3;
      #pragma unroll
      for (int reg=0;reg<4;reg++){
        float v = C[reg] - cl[t];
        h[(rowbase + q*4 + reg)*64 + t*16 + c] = f2bf(v);
        if (reg==0){ ps0 = fmaf(v, asl[t], ps0); pd0 = fmaf(v, adl[t], pd0); }
        if (reg==1){ ps1 = fmaf(v, asl[t], ps1); pd1 = fmaf(v, adl[t], pd1); }
        if (reg==2){ ps2 = fmaf(v, asl[t], ps2); pd2 = fmaf(v, adl[t], pd2); }
        if (reg==3){ ps3 = fmaf(v, asl[t], ps3); pd3 = fmaf(v, adl[t], pd3); }
      }
    }
    #pragma unroll
    for (int off=1; off<16; off<<=1){
      ps0 += __shfl_xor(ps0, off); pd0 += __shfl_xor(pd0, off);
      ps1 += __shfl_xor(ps1, off); pd1 += __shfl_xor(pd1, off);
      ps2 += __shfl_xor(ps2, off); pd2 += __shfl_xor(pd2, off);
      ps3 += __shfl_xor(ps3, off); pd3 += __shfl_xor(pd3, off);
    }
    if (c == 0){
      size_t r0 = rowbase + q*4;
      als[r0+0]=ps0; als[r0+1]=ps1; als[r0+2]=ps2; als[r0+3]=ps3;
      ald[r0+0]=pd0; ald[r0+1]=pd1; ald[r0+2]=pd2; ald[r0+3]=pd3;
    }
  }
}

// ---------------- per-(graph,slot) packed entry: src | (bf16 w << 16) ----------------
__global__ __launch_bounds__(256) void wfill_k(const u16* __restrict__ ell_src, const u16* __restrict__ ell_dst,
                        const float* __restrict__ als, const float* __restrict__ ald,
                        u32* __restrict__ epack, int cap, int log2NS)
{
  int slot = blockIdx.x*256 + threadIdx.x;
  int g = blockIdx.y;
  int s = ell_src[slot];
  u32 w = 0;
  if (s != 0xFFFF){
    int d = ell_dst[slot];
    int base = g << log2NS;
    float e = als[base + s] + ald[base + d];
    w = (u32)f2bf(__expf(lrelu(e))) << 16;
  }
  epack[(size_t)g*cap + slot] = (u32)(s & 0xFFFF) | w;
}

// ---------------- GAT gather + softmax + bias + relu + pairwise max-pool ----------------
// wave = 8 groups x 8 lanes; group g owns node (wv*8+g); no cross-group sum reduction.
__global__ __launch_bounds__(256) void gat_pool_k(const u16* __restrict__ h, const float* __restrict__ bias,
                      const int* __restrict__ indptr2, const int* __restrict__ counts,
                      const u32* __restrict__ epack, u16* __restrict__ P,
                      int log2NS, int cap, int nwaves)
{
  const int l = threadIdx.x & 63;
  const int g = l >> 3;
  const int o = l & 7;
  const int NB  = gridDim.x;
  const int bid = blockIdx.x;
  const int lb  = (bid & 7) * (NB >> 3) + (bid >> 3);   // XCD swizzle
  const int wv  = lb * 4 + (int)(threadIdx.x >> 6);
  if (wv >= nwaves) return;

  const int wbits = log2NS - 3;
  const int b = wv >> wbits;
  const int d = ((wv & ((1 << wbits) - 1)) << 3) + g;    // this group's node
  const u32* hb = (const u32*)(h + ((((size_t)b << log2NS)) << 6)) + (o << 2);
  const u32* erow = epack + (size_t)b * cap;

  const int p0  = indptr2[d];
  const int cnt = counts[d] + 1;                          // deg + self

  const float* bp = bias + (o << 3);
  float4 bA = *(const float4*)(bp);
  float4 bB = *(const float4*)(bp + 4);

  v2f a01={0.f,0.f}, a23={0.f,0.f}, a45={0.f,0.f}, a67={0.f,0.f};
  float z = 0.f;

  u32 e = erow[p0];
  for (int it = 0; it < cnt; ++it){
    u32 e_n = erow[p0 + it + 1];                          // prefetch (padded slots exist)
    int s = e & 0xffff;
    float w = __uint_as_float(e & 0xffff0000u);
    const u32* hp = hb + ((size_t)s << 5);
    u32 r0 = hp[0], r1 = hp[1], r2 = hp[2], r3 = hp[3];
    z += w;
    v2f w2 = {w, w};
    a01 += (v2f){ __uint_as_float(r0 << 16), __uint_as_float(r0 & 0xffff0000u) } * w2;
    a23 += (v2f){ __uint_as_float(r1 << 16), __uint_as_float(r1 & 0xffff0000u) } * w2;
    a45 += (v2f){ __uint_as_float(r2 << 16), __uint_as_float(r2 & 0xffff0000u) } * w2;
    a67 += (v2f){ __uint_as_float(r3 << 16), __uint_as_float(r3 & 0xffff0000u) } * w2;
    e = e_n;
  }

  float rz = __builtin_amdgcn_rcpf(z);
  float q0 = fmaxf(fmaf(a01.x, rz, bA.x), 0.f);
  float q1 = fmaxf(fmaf(a01.y, rz, bA.y), 0.f);
  float q2 = fmaxf(fmaf(a23.x, rz, bA.z), 0.f);
  float q3 = fmaxf(fmaf(a23.y, rz, bA.w), 0.f);
  float q4 = fmaxf(fmaf(a45.x, rz, bB.x), 0.f);
  float q5 = fmaxf(fmaf(a45.y, rz, bB.y), 0.f);
  float q6 = fmaxf(fmaf(a67.x, rz, bB.z), 0.f);
  float q7 = fmaxf(fmaf(a67.y, rz, bB.w), 0.f);
  q0 = fmaxf(q0, __shfl_xor(q0, 8));
  q1 = fmaxf(q1, __shfl_xor(q1, 8));
  q2 = fmaxf(q2, __shfl_xor(q2, 8));
  q3 = fmaxf(q3, __shfl_xor(q3, 8));
  q4 = fmaxf(q4, __shfl_xor(q4, 8));
  q5 = fmaxf(q5, __shfl_xor(q5, 8));
  q6 = fmaxf(q6, __shfl_xor(q6, 8));
  q7 = fmaxf(q7, __shfl_xor(q7, 8));
  if ((g & 1) == 0){
    u32 w0 = (u32)f2bf(q0) | ((u32)f2bf(q1) << 16);
    u32 w1 = (u32)f2bf(q2) | ((u32)f2bf(q3) << 16);
    u32 w2p = (u32)f2bf(q4) | ((u32)f2bf(q5) << 16);
    u32 w3 = (u32)f2bf(q6) | ((u32)f2bf(q7) << 16);
    size_t prow = (size_t)wv*4 + (g >> 1);
    ((int4*)(P + (prow << 6)))[o] = make_int4((int)w0,(int)w1,(int)w2p,(int)w3);
  }
}

// ---------------- BatchNorm stats (2-stage) ----------------
__global__ __launch_bounds__(256) void bn_stats_k(const u16* __restrict__ P, float* __restrict__ scratch, int nrows){
  const int l = threadIdx.x & 63;
  int gw = blockIdx.x*4 + (threadIdx.x>>6);
  int GW = gridDim.x*4;
  float s = 0.f, s2 = 0.f;
  for (int r = gw; r < nrows; r += GW){
    float v = bf2f(P[(size_t)r*64 + l]);
    s += v; s2 = fmaf(v, v, s2);
  }
  __shared__ float ls[256], ls2[256];
  ls[threadIdx.x] = s; ls2[threadIdx.x] = s2;
  __syncthreads();
  if (threadIdx.x < 64){
    float S  = ls[threadIdx.x] + ls[threadIdx.x+64] + ls[threadIdx.x+128] + ls[threadIdx.x+192];
    float S2 = ls2[threadIdx.x] + ls2[threadIdx.x+64] + ls2[threadIdx.x+128] + ls2[threadIdx.x+192];
    scratch[blockIdx.x*128 + threadIdx.x] = S;
    scratch[blockIdx.x*128 + 64 + threadIdx.x] = S2;
  }
}

__global__ __launch_bounds__(128) void bn_finish_k(const float* __restrict__ scratch, float* __restrict__ stats,
                                                   int nblocks, float invN){
  __shared__ float accs[128];
  int j = threadIdx.x;
  float s = 0.f;
  for (int b=0;b<nblocks;b++) s += scratch[b*128 + j];
  accs[j] = s;
  __syncthreads();
  if (j < 64){
    float m = accs[j]*invN;
    float var = accs[j+64]*invN - m*m;
    stats[j] = m;
    stats[64+j] = rsqrtf(var + BN_EPS);
  }
}

// ---------------- final BN apply: bf16 P -> f32 out ----------------
__global__ __launch_bounds__(256) void bn_apply_k(const u32* __restrict__ P2, const float* __restrict__ stats,
                                                  float4* __restrict__ out, int nq){
  int t = blockIdx.x*256 + threadIdx.x;
  if (t >= nq) return;
  int l = (t*4) & 63;
  u32 v0 = P2[t*2], v1 = P2[t*2+1];
  float4 r;
  r.x = (__uint_as_float((v0 & 0xffffu) << 16) - stats[l+0]) * stats[64+l+0];
  r.y = (__uint_as_float( v0 & 0xffff0000u    ) - stats[l+1]) * stats[64+l+1];
  r.z = (__uint_as_float((v1 & 0xffffu) << 16) - stats[l+2]) * stats[64+l+2];
  r.w = (__uint_as_float( v1 & 0xffff0000u    ) - stats[l+3]) * stats[64+l+3];
  out[t] = r;
}

// ---------------- launcher ----------------
extern "C" void kernel_launch(void* const* d_in, const int* in_sizes, int n_in,
                              void* d_out, int out_size, void* d_ws, size_t ws_size,
                              hipStream_t stream)
{
  const float* x      = (const float*)d_in[0];
  const float* Wl[3]  = {(const float*)d_in[1], (const float*)d_in[7],  (const float*)d_in[13]};
  const float* asl[3] = {(const float*)d_in[2], (const float*)d_in[8],  (const float*)d_in[14]};
  const float* adl[3] = {(const float*)d_in[3], (const float*)d_in[9],  (const float*)d_in[15]};
  const float* bl[3]  = {(const float*)d_in[4], (const float*)d_in[10], (const float*)d_in[16]};
  const int*   el[3]  = {(const int*)d_in[5],   (const int*)d_in[11],   (const int*)d_in[17]};

  const int NS[4]  = {4096, 2048, 1024, 512};
  const int EPB[3] = {32768, 16384, 8192};
  const int LOG2NS[3] = {12, 11, 10};
  const int ECAP[3] = {32768+4*4096, 16384+4*2048, 8192+4*1024};  // 49152, 24576, 12288
  const int BATCH = 256;

  char* ws = (char*)d_ws;
  size_t off = 0;
  auto alloc = [&](size_t bytes)->char*{
    char* p = ws + off; off += (bytes + 255) & ~(size_t)255; return p;
  };

  u16*   hbuf    = (u16*)alloc((size_t)BATCH*NS[0]*64*2);            // 128 MB
  u16*   Pbuf    = (u16*)alloc((size_t)BATCH*NS[1]*64*2);            //  64 MB
  u32*   epack   = (u32*)alloc(((size_t)BATCH*ECAP[0] + 64)*4);      //  50 MB
  float* als     = (float*)alloc((size_t)BATCH*NS[0]*4);             //   4 MB
  float* ald     = (float*)alloc((size_t)BATCH*NS[0]*4);             //   4 MB
  float* scratch = (float*)alloc(256*128*4);
  float* stats   = (float*)alloc(384*4);
  u16*   wswz    = (u16*)alloc(8*64*8*2);
  float* cvec    = (float*)alloc(64*4);
  int* counts_all = (int*)alloc((size_t)(NS[0]+NS[1]+NS[2])*4);
  int* cursor_all = (int*)alloc((size_t)(NS[0]+NS[1]+NS[2])*4);
  int *counts[3], *cursor[3], *indptr2[3];
  u16 *ell_src[3], *ell_dst[3];
  counts[0]=counts_all; counts[1]=counts_all+NS[0]; counts[2]=counts_all+NS[0]+NS[1];
  cursor[0]=cursor_all; cursor[1]=cursor_all+NS[0]; cursor[2]=cursor_all+NS[0]+NS[1];
  for (int i=0;i<3;i++){
    indptr2[i] = (int*)alloc((size_t)(NS[i]+1)*4);
    ell_src[i] = (u16*)alloc((size_t)(ECAP[i]+16)*2);
    ell_dst[i] = (u16*)alloc((size_t)(ECAP[i]+16)*2);
  }
  if (off > ws_size) return;

  // ---- fused ELL build ----
  int ctot = NS[0]+NS[1]+NS[2];
  zero_int_k<<<(ctot+255)/256, 256, 0, stream>>>(counts_all, ctot);
  {
    dim3 gdef((ECAP[0]+16+255)/256, 3);
    ell_default_all_k<<<gdef, 256, 0, stream>>>(ell_src[0], ell_src[1], ell_src[2],
                                                ell_dst[0], ell_dst[1], ell_dst[2],
                                                ECAP[0]+16, ECAP[1]+16, ECAP[2]+16);
    dim3 ghist(EPB[0]/256, 3);
    hist_all_k<<<ghist, 256, 0, stream>>>(el[0], el[1], el[2], counts[0], counts[1], counts[2],
                                          EPB[0], EPB[1], EPB[2]);
    scan_all_k<<<3, 1024, 0, stream>>>(counts[0], counts[1], counts[2],
                                       indptr2[0], indptr2[1], indptr2[2],
                                       cursor[0], cursor[1], cursor[2],
                                       ell_src[0], ell_src[1], ell_src[2],
                                       ell_dst[0], ell_dst[1], ell_dst[2],
                                       NS[0], NS[1], NS[2]);
    scatter_all_k<<<ghist, 256, 0, stream>>>(el[0], el[1], el[2],
                                             cursor[0], cursor[1], cursor[2],
                                             ell_src[0], ell_src[1], ell_src[2],
                                             ell_dst[0], ell_dst[1], ell_dst[2],
                                             EPB[0], EPB[1], EPB[2]);
  }

  // ---- layers ----
  for (int i=0;i<3;i++){
    int ntot = BATCH*NS[i];

    if (i==0){
      gemm3_k<<<1024, 256, 0, stream>>>(x, Wl[0], asl[0], adl[0], hbuf, als, ald, ntot/8);
    } else {
      prep_w_k<<<1, 64, 0, stream>>>(Wl[i], stats + (i-1)*128, wswz, cvec);
      gemm64_mfma_k<<<2048, 256, 0, stream>>>(Pbuf, wswz, cvec, asl[i], adl[i],
                                              hbuf, als, ald, ntot/16);
    }

    dim3 wgrid(ECAP[i]/256, BATCH);
    wfill_k<<<wgrid, 256, 0, stream>>>(ell_src[i], ell_dst[i], als, ald, epack, ECAP[i], LOG2NS[i]);

    int nwaves = ntot/8;
    gat_pool_k<<<nwaves/4, 256, 0, stream>>>(hbuf, bl[i], indptr2[i], counts[i], epack,
                                             Pbuf, LOG2NS[i], ECAP[i], nwaves);

    bn_stats_k<<<256, 256, 0, stream>>>(Pbuf, scratch, ntot/2);
    bn_finish_k<<<1, 128, 0, stream>>>(scratch, stats + i*128, 256, 1.0f/(float)(ntot/2));
  }

  // ---- final BN materialization into d_out ----
  int nq = out_size/4;
  bn_apply_k<<<(nq+255)/256, 256, 0, stream>>>((const u32*)Pbuf, stats + 256, (float4*)d_out, nq);
}

// Round 7
// 610.697 us; speedup vs baseline: 3.7284x; 1.5521x over previous
//
#include <hip/hip_runtime.h>
#include <stdint.h>

#define NEG_SLOPE 0.2f
#define BN_EPS 1e-5f

typedef unsigned short u16;
typedef unsigned int   u32;
typedef __attribute__((ext_vector_type(2))) float  v2f;
typedef __attribute__((ext_vector_type(4))) float  f32x4;
typedef __attribute__((ext_vector_type(8))) short  short8;

__device__ __forceinline__ float lrelu(float x){ return fmaxf(x, NEG_SLOPE*x); }
__device__ __forceinline__ float bf2f(u16 u){ return __uint_as_float(((u32)u) << 16); }
__device__ __forceinline__ u16 f2bf(float f){           // round-to-nearest-even
  u32 u = __float_as_uint(f);
  return (u16)((u + 0x7fffu + ((u >> 16) & 1u)) >> 16);
}

// ---------------- build phase ----------------
// y=0: zero counts; y=1..3: fill ell_sd[L] with 0xFFFFFFFF
__global__ __launch_bounds__(256) void init_k(int* __restrict__ counts, u32* __restrict__ s0,
                                              u32* __restrict__ s1, u32* __restrict__ s2,
                                              int nc, int n0, int n1, int n2){
  int t = blockIdx.x*256 + threadIdx.x;
  int y = blockIdx.y;
  if (y==0){ if (t<nc) counts[t]=0; }
  else {
    u32* sd = (y==1)?s0:(y==2)?s1:s2;
    int n   = (y==1)?n0:(y==2)?n1:n2;
    if (t<n) sd[t]=0xFFFFFFFFu;
  }
}

__global__ __launch_bounds__(256) void hist_all_k(const int* __restrict__ el0, const int* __restrict__ el1,
                                                  const int* __restrict__ el2, int* __restrict__ c0,
                                                  int* __restrict__ c1, int* __restrict__ c2,
                                                  int n0, int n1, int n2){
  int t = blockIdx.x*256 + threadIdx.x;
  int L = blockIdx.y;
  const int* dst = (L==0)?(el0+n0):(L==1)?(el1+n1):(el2+n2);
  int* counts    = (L==0)?c0:(L==1)?c1:c2;
  int n          = (L==0)?n0:(L==1)?n1:n2;
  if (t < n) atomicAdd(&counts[dst[t]], 1);
}

// padded scan per layer: row len = (deg+4)&~3 (>= deg+1), self at slot 0
__global__ __launch_bounds__(1024) void scan_all_k(int* __restrict__ c0, int* __restrict__ c1, int* __restrict__ c2,
                         int* __restrict__ ip0, int* __restrict__ ip1, int* __restrict__ ip2,
                         int* __restrict__ cu0, int* __restrict__ cu1, int* __restrict__ cu2,
                         u32* __restrict__ sd0, u32* __restrict__ sd1, u32* __restrict__ sd2,
                         int n0, int n1, int n2){
  int L = blockIdx.x;
  const int* counts = (L==0)?c0:(L==1)?c1:c2;
  int* indptr2      = (L==0)?ip0:(L==1)?ip1:ip2;
  int* cursor       = (L==0)?cu0:(L==1)?cu1:cu2;
  u32* sd           = (L==0)?sd0:(L==1)?sd1:sd2;
  int n             = (L==0)?n0:(L==1)?n1:n2;
  __shared__ int part[1024];
  int tid = threadIdx.x;
  int base = tid*4;
  int v0=0,v1=0,v2=0,v3=0;
  if (base+0<n) v0 = (counts[base+0]+4)&~3;
  if (base+1<n) v1 = (counts[base+1]+4)&~3;
  if (base+2<n) v2 = (counts[base+2]+4)&~3;
  if (base+3<n) v3 = (counts[base+3]+4)&~3;
  part[tid] = v0+v1+v2+v3;
  __syncthreads();
  for (int off=1; off<1024; off<<=1){
    int t2 = (tid>=off)?part[tid-off]:0;
    __syncthreads();
    part[tid] += t2;
    __syncthreads();
  }
  int run = (tid>0)?part[tid-1]:0;
  if (base+0<n){ indptr2[base+0]=run; cursor[base+0]=run+1; sd[run]=(u32)(base+0)|((u32)(base+0)<<16); run+=v0; }
  if (base+1<n){ indptr2[base+1]=run; cursor[base+1]=run+1; sd[run]=(u32)(base+1)|((u32)(base+1)<<16); run+=v1; }
  if (base+2<n){ indptr2[base+2]=run; cursor[base+2]=run+1; sd[run]=(u32)(base+2)|((u32)(base+2)<<16); run+=v2; }
  if (base+3<n){ indptr2[base+3]=run; cursor[base+3]=run+1; sd[run]=(u32)(base+3)|((u32)(base+3)<<16); run+=v3; }
  if (tid==0) indptr2[n] = part[1023];
}

__global__ __launch_bounds__(256) void scatter_all_k(const int* __restrict__ el0, const int* __restrict__ el1,
                         const int* __restrict__ el2, int* __restrict__ cu0, int* __restrict__ cu1,
                         int* __restrict__ cu2, u32* __restrict__ sd0, u32* __restrict__ sd1,
                         u32* __restrict__ sd2, int n0, int n1, int n2){
  int t = blockIdx.x*256 + threadIdx.x;
  int L = blockIdx.y;
  const int* el = (L==0)?el0:(L==1)?el1:el2;
  int* cursor   = (L==0)?cu0:(L==1)?cu1:cu2;
  u32* sd       = (L==0)?sd0:(L==1)?sd1:sd2;
  int n         = (L==0)?n0:(L==1)?n1:n2;
  if (t < n){
    int dd = el[n + t];
    int p = atomicAdd(&cursor[dd], 1);
    sd[p] = (u32)el[t] | ((u32)dd << 16);
  }
}

// counting sort of pool-pairs by max(deg) -> perm (shared by all graphs)
__global__ __launch_bounds__(1024) void pairsort_k(const int* __restrict__ c0, const int* __restrict__ c1,
                         const int* __restrict__ c2, u16* __restrict__ pm0, u16* __restrict__ pm1,
                         u16* __restrict__ pm2, int np0, int np1, int np2){
  int L = blockIdx.x;
  const int* counts = (L==0)?c0:(L==1)?c1:c2;
  u16* perm = (L==0)?pm0:(L==1)?pm1:pm2;
  int np    = (L==0)?np0:(L==1)?np1:np2;
  __shared__ int hist[64];
  __shared__ int pos[64];
  int t = threadIdx.x;
  if (t < 64) hist[t] = 0;
  __syncthreads();
  for (int p=t; p<np; p+=1024){
    int k = min(max(counts[2*p], counts[2*p+1]), 63);
    atomicAdd(&hist[k], 1);
  }
  __syncthreads();
  if (t == 0){ int run=0; for (int i=0;i<64;i++){ pos[i]=run; run+=hist[i]; } }
  __syncthreads();
  for (int p=t; p<np; p+=1024){
    int k = min(max(counts[2*p], counts[2*p+1]), 63);
    int q = atomicAdd(&pos[k], 1);
    perm[q] = (u16)p;
  }
}

// ---------------- layer-0 GEMM: x[n,3] @ W0[3,64] -> h bf16, al_s, al_d ----------------
__global__ __launch_bounds__(256) void gemm3_k(const float* __restrict__ x, const float* __restrict__ Wg,
                        const float* __restrict__ asrc, const float* __restrict__ adst,
                        u16* __restrict__ h, float* __restrict__ als, float* __restrict__ ald, int nrows8)
{
  const int l = threadIdx.x & 63;
  const int g = l >> 3;
  const int o = l & 7;
  float W0[8], W1[8], W2[8];
  float vs0=0.f,vs1=0.f,vs2=0.f,vd0=0.f,vd1=0.f,vd2=0.f;
  #pragma unroll
  for (int j=0;j<8;j++){
    W0[j] = Wg[      o*8 + j];
    W1[j] = Wg[ 64 + o*8 + j];
    W2[j] = Wg[128 + o*8 + j];
    float as = asrc[o*8 + j], ad = adst[o*8 + j];
    vs0 = fmaf(W0[j], as, vs0); vs1 = fmaf(W1[j], as, vs1); vs2 = fmaf(W2[j], as, vs2);
    vd0 = fmaf(W0[j], ad, vd0); vd1 = fmaf(W1[j], ad, vd1); vd2 = fmaf(W2[j], ad, vd2);
  }
  #pragma unroll
  for (int off=1; off<8; off<<=1){
    vs0 += __shfl_xor(vs0,off); vs1 += __shfl_xor(vs1,off); vs2 += __shfl_xor(vs2,off);
    vd0 += __shfl_xor(vd0,off); vd1 += __shfl_xor(vd1,off); vd2 += __shfl_xor(vd2,off);
  }
  int wv = blockIdx.x*4 + (int)(threadIdx.x>>6);
  int stride = gridDim.x*4;
  for (int blk = wv; blk < nrows8; blk += stride){
    int r = blk*8 + g;
    float x0 = x[(size_t)r*3+0];
    float x1 = x[(size_t)r*3+1];
    float x2 = x[(size_t)r*3+2];
    u32 pk[4];
    #pragma unroll
    for (int j=0;j<8;j+=2){
      float a0 = fmaf(x0, W0[j],   fmaf(x1, W1[j],   x2*W2[j]));
      float a1 = fmaf(x0, W0[j+1], fmaf(x1, W1[j+1], x2*W2[j+1]));
      pk[j>>1] = (u32)f2bf(a0) | ((u32)f2bf(a1) << 16);
    }
    ((int4*)(h + ((size_t)r << 6)))[o] = make_int4((int)pk[0],(int)pk[1],(int)pk[2],(int)pk[3]);
    if (o == 0){
      als[r] = fmaf(x2, vs2, fmaf(x1, vs1, x0*vs0));
      ald[r] = fmaf(x2, vd2, fmaf(x1, vd1, x0*vd0));
    }
  }
}

// ---------------- prep (layers 1/2): BN finish of prev layer + W' frags + als/ald B-tile ----------------
__global__ __launch_bounds__(128) void prep_w_k(const float* __restrict__ W, const float* __restrict__ asrc,
                        const float* __restrict__ adst, const float* __restrict__ scratch, float invN,
                        u16* __restrict__ wswz, float* __restrict__ cvec){
  __shared__ float mean_s[64], rstd_s[64], vs_s[64], vd_s[64], cv_s[64], acc[128];
  int t = threadIdx.x;
  float s = 0.f;
  #pragma unroll 8
  for (int b2=0;b2<256;b2++) s += scratch[b2*128 + t];
  acc[t] = s;
  __syncthreads();
  if (t < 64){
    float m = acc[t]*invN;
    float var = acc[64+t]*invN - m*m;
    mean_s[t] = m; rstd_s[t] = rsqrtf(var + BN_EPS);
  }
  __syncthreads();
  if (t < 64){
    float c = 0.f;
    for (int k=0;k<64;k++) c = fmaf(mean_s[k]*rstd_s[k], W[k*64+t], c);
    cv_s[t] = c; cvec[t] = c;
    float vs = 0.f, vd = 0.f;
    for (int col=0; col<64; col++){
      float wv = W[t*64+col];
      vs = fmaf(wv, asrc[col], vs);
      vd = fmaf(wv, adst[col], vd);
    }
    vs_s[t] = rstd_s[t]*vs; vd_s[t] = rstd_s[t]*vd;
  }
  __syncthreads();
  if (t == 0){
    float cs=0.f, cd=0.f;
    for (int col=0; col<64; col++){ cs = fmaf(cv_s[col], asrc[col], cs); cd = fmaf(cv_s[col], adst[col], cd); }
    cvec[64] = cs; cvec[65] = cd;
  }
  if (t < 64){
    #pragma unroll
    for (int f=0; f<8; f++){
      int tt = f >> 1, ch = f & 1;
      #pragma unroll
      for (int j=0; j<8; j++){
        int k   = ch*32 + (t>>4)*8 + j;
        int col = tt*16 + (t&15);
        wswz[(f*64 + t)*8 + j] = f2bf(rstd_s[k] * W[k*64 + col]);
      }
    }
    #pragma unroll
    for (int f=8; f<10; f++){
      int ch = f - 8;
      #pragma unroll
      for (int j=0; j<8; j++){
        int k = ch*32 + (t>>4)*8 + j;
        int colp = t & 15;
        float val = (colp==0)? vs_s[k] : (colp==1)? vd_s[k] : 0.f;
        wswz[(f*64 + t)*8 + j] = f2bf(val);
      }
    }
  }
}

// ---------------- layers 1/2 GEMM via MFMA: h = P @ W' - c; als/ald via augmented B-tile ----------------
__global__ __launch_bounds__(256) void gemm64_mfma_k(const u16* __restrict__ Pin, const u16* __restrict__ wswz,
                        const float* __restrict__ cvec,
                        u16* __restrict__ h, float* __restrict__ als, float* __restrict__ ald, int nblk16)
{
  const int l = threadIdx.x & 63;
  const int q = l >> 4;
  const int c = l & 15;
  short8 B[10];
  const int4* wsw = (const int4*)wswz;
  #pragma unroll
  for (int f=0; f<10; f++){
    int4 v = wsw[f*64 + l];
    B[f] = *(short8*)&v;
  }
  float cl[4];
  #pragma unroll
  for (int t=0;t<4;t++) cl[t] = cvec[t*16+c];
  const float const_s = cvec[64], const_d = cvec[65];
  int gw = blockIdx.x*4 + (int)(threadIdx.x>>6);
  int stride = gridDim.x*4;
  for (int blk = gw; blk < nblk16; blk += stride){
    size_t rowbase = (size_t)blk*16;
    const int4* arow = (const int4*)(Pin + (rowbase + c)*64);
    int4 a0v = arow[q];
    int4 a1v = arow[4+q];
    short8 A0 = *(short8*)&a0v, A1 = *(short8*)&a1v;
    f32x4 C0={0.f,0.f,0.f,0.f}, C1=C0, C2=C0, C3=C0, C4=C0;
    C0 = __builtin_amdgcn_mfma_f32_16x16x32_bf16(A0, B[0], C0, 0,0,0);
    C0 = __builtin_amdgcn_mfma_f32_16x16x32_bf16(A1, B[1], C0, 0,0,0);
    C1 = __builtin_amdgcn_mfma_f32_16x16x32_bf16(A0, B[2], C1, 0,0,0);
    C1 = __builtin_amdgcn_mfma_f32_16x16x32_bf16(A1, B[3], C1, 0,0,0);
    C2 = __builtin_amdgcn_mfma_f32_16x16x32_bf16(A0, B[4], C2, 0,0,0);
    C2 = __builtin_amdgcn_mfma_f32_16x16x32_bf16(A1, B[5], C2, 0,0,0);
    C3 = __builtin_amdgcn_mfma_f32_16x16x32_bf16(A0, B[6], C3, 0,0,0);
    C3 = __builtin_amdgcn_mfma_f32_16x16x32_bf16(A1, B[7], C3, 0,0,0);
    C4 = __builtin_amdgcn_mfma_f32_16x16x32_bf16(A0, B[8], C4, 0,0,0);
    C4 = __builtin_amdgcn_mfma_f32_16x16x32_bf16(A1, B[9], C4, 0,0,0);
    #pragma unroll
    for (int t=0;t<4;t++){
      f32x4 C = (t==0)?C0:(t==1)?C1:(t==2)?C2:C3;
      #pragma unroll
      for (int reg=0;reg<4;reg++){
        h[(rowbase + q*4 + reg)*64 + t*16 + c] = f2bf(C[reg] - cl[t]);
      }
    }
    if (c == 0){
      #pragma unroll
      for (int reg=0;reg<4;reg++) als[rowbase + q*4 + reg] = C4[reg] - const_s;
    } else if (c == 1){
      #pragma unroll
      for (int reg=0;reg<4;reg++) ald[rowbase + q*4 + reg] = C4[reg] - const_d;
    }
  }
}

// ---------------- per-(graph,slot) packed entry: src | (bf16 w << 16) ----------------
__global__ __launch_bounds__(256) void wfill_k(const u32* __restrict__ ell_sd,
                        const float* __restrict__ als, const float* __restrict__ ald,
                        u32* __restrict__ epack, int cap, int log2NS)
{
  int slot = blockIdx.x*256 + threadIdx.x;
  int g = blockIdx.y;
  u32 v = ell_sd[slot];
  int nmask = (1<<log2NS)-1;
  int s = (int)(v & 0xffffu);
  int d = (int)(v >> 16);
  int base = g << log2NS;
  float e = als[base + (s & nmask)] + ald[base + (d & nmask)];
  u32 w = (v == 0xFFFFFFFFu) ? 0u : ((u32)f2bf(__expf(lrelu(e))) << 16);
  epack[(size_t)g*cap + slot] = (v & 0xffffu) | w;
}

// ---------------- GAT gather + softmax + bias + relu + pairwise max-pool ----------------
// wave = 8 groups x 8 lanes; group g owns node 2*perm[pairslot]+(g&1); 2-deep pipeline.
__global__ __launch_bounds__(256) void gat_pool_k(const u16* __restrict__ h, const float* __restrict__ bias,
                      const int* __restrict__ indptr2, const int* __restrict__ counts,
                      const u16* __restrict__ perm, const u32* __restrict__ epack, u16* __restrict__ P,
                      int log2NS, int cap, int nwaves)
{
  const int l = threadIdx.x & 63;
  const int g = l >> 3;
  const int o = l & 7;
  const int NB  = gridDim.x;
  const int bid = blockIdx.x;
  const int lb  = (bid & 7) * (NB >> 3) + (bid >> 3);   // XCD swizzle: graphs contiguous per XCD
  const int wv  = lb * 4 + (int)(threadIdx.x >> 6);
  if (wv >= nwaves) return;

  const int wbits = log2NS - 3;
  const int b    = wv >> wbits;
  const int widx = wv & ((1 << wbits) - 1);
  const int pairslot = widx*4 + (g >> 1);
  const int prow = perm[pairslot];
  const int d = 2*prow + (g & 1);
  const int nmask = (1 << log2NS) - 1;
  const u32* hb = (const u32*)(h + ((((size_t)b << log2NS)) << 6)) + (o << 2);
  const u32* erow = epack + (size_t)b * cap;

  const int p0  = indptr2[d];
  const int cnt = counts[d] + 1;

  const float* bp = bias + (o << 3);
  float4 bA = *(const float4*)(bp);
  float4 bB = *(const float4*)(bp + 4);

  v2f a01={0.f,0.f}, a23={0.f,0.f}, a45={0.f,0.f}, a67={0.f,0.f};
  float z = 0.f;

  u32 eA = erow[p0];
  int sA = (int)(eA & 0xffffu) & nmask;
  const u32* hpA = hb + ((size_t)sA << 5);
  u32 rA0=hpA[0], rA1=hpA[1], rA2=hpA[2], rA3=hpA[3];
  u32 eB = erow[p0 + 1];

  for (int it = 0; it < cnt; ++it){
    int sB = (int)(eB & 0xffffu) & nmask;
    const u32* hpB = hb + ((size_t)sB << 5);
    u32 rB0=hpB[0], rB1=hpB[1], rB2=hpB[2], rB3=hpB[3];   // h(it+1), a full iter early
    u32 eC = erow[p0 + it + 2];                            // meta(it+2)
    float w = __uint_as_float(eA & 0xffff0000u);
    z += w;
    v2f w2 = {w, w};
    a01 += (v2f){ __uint_as_float(rA0 << 16), __uint_as_float(rA0 & 0xffff0000u) } * w2;
    a23 += (v2f){ __uint_as_float(rA1 << 16), __uint_as_float(rA1 & 0xffff0000u) } * w2;
    a45 += (v2f){ __uint_as_float(rA2 << 16), __uint_as_float(rA2 & 0xffff0000u) } * w2;
    a67 += (v2f){ __uint_as_float(rA3 << 16), __uint_as_float(rA3 & 0xffff0000u) } * w2;
    eA = eB; eB = eC;
    rA0 = rB0; rA1 = rB1; rA2 = rB2; rA3 = rB3;
  }

  float rz = __builtin_amdgcn_rcpf(z);
  float q0 = fmaxf(fmaf(a01.x, rz, bA.x), 0.f);
  float q1 = fmaxf(fmaf(a01.y, rz, bA.y), 0.f);
  float q2 = fmaxf(fmaf(a23.x, rz, bA.z), 0.f);
  float q3 = fmaxf(fmaf(a23.y, rz, bA.w), 0.f);
  float q4 = fmaxf(fmaf(a45.x, rz, bB.x), 0.f);
  float q5 = fmaxf(fmaf(a45.y, rz, bB.y), 0.f);
  float q6 = fmaxf(fmaf(a67.x, rz, bB.z), 0.f);
  float q7 = fmaxf(fmaf(a67.y, rz, bB.w), 0.f);
  q0 = fmaxf(q0, __shfl_xor(q0, 8));
  q1 = fmaxf(q1, __shfl_xor(q1, 8));
  q2 = fmaxf(q2, __shfl_xor(q2, 8));
  q3 = fmaxf(q3, __shfl_xor(q3, 8));
  q4 = fmaxf(q4, __shfl_xor(q4, 8));
  q5 = fmaxf(q5, __shfl_xor(q5, 8));
  q6 = fmaxf(q6, __shfl_xor(q6, 8));
  q7 = fmaxf(q7, __shfl_xor(q7, 8));
  if ((g & 1) == 0){
    u32 w0 = (u32)f2bf(q0) | ((u32)f2bf(q1) << 16);
    u32 w1 = (u32)f2bf(q2) | ((u32)f2bf(q3) << 16);
    u32 w2p = (u32)f2bf(q4) | ((u32)f2bf(q5) << 16);
    u32 w3 = (u32)f2bf(q6) | ((u32)f2bf(q7) << 16);
    size_t prowg = ((size_t)b << (log2NS - 1)) + prow;
    ((int4*)(P + (prowg << 6)))[o] = make_int4((int)w0,(int)w1,(int)w2p,(int)w3);
  }
}

// ---------------- BatchNorm stats (stage 1) ----------------
__global__ __launch_bounds__(256) void bn_stats_k(const u16* __restrict__ P, float* __restrict__ scratch, int iters){
  const int l = threadIdx.x & 63;
  int gw = blockIdx.x*4 + (threadIdx.x>>6);
  int GW = gridDim.x*4;
  float s = 0.f, s2 = 0.f;
  #pragma unroll 4
  for (int i = 0; i < iters; i++){
    int r = gw + i*GW;
    float v = bf2f(P[(size_t)r*64 + l]);
    s += v; s2 = fmaf(v, v, s2);
  }
  __shared__ float ls[256], ls2[256];
  ls[threadIdx.x] = s; ls2[threadIdx.x] = s2;
  __syncthreads();
  if (threadIdx.x < 64){
    float S  = ls[threadIdx.x] + ls[threadIdx.x+64] + ls[threadIdx.x+128] + ls[threadIdx.x+192];
    float S2 = ls2[threadIdx.x] + ls2[threadIdx.x+64] + ls2[threadIdx.x+128] + ls2[threadIdx.x+192];
    scratch[blockIdx.x*128 + threadIdx.x] = S;
    scratch[blockIdx.x*128 + 64 + threadIdx.x] = S2;
  }
}

__global__ __launch_bounds__(128) void bn_finish_k(const float* __restrict__ scratch, float* __restrict__ stats,
                                                   int nblocks, float invN){
  __shared__ float accs[128];
  int j = threadIdx.x;
  float s = 0.f;
  #pragma unroll 8
  for (int b=0;b<nblocks;b++) s += scratch[b*128 + j];
  accs[j] = s;
  __syncthreads();
  if (j < 64){
    float m = accs[j]*invN;
    float var = accs[j+64]*invN - m*m;
    stats[j] = m;
    stats[64+j] = rsqrtf(var + BN_EPS);
  }
}

// ---------------- final BN apply: bf16 P -> f32 out ----------------
__global__ __launch_bounds__(256) void bn_apply_k(const u32* __restrict__ P2, const float* __restrict__ stats,
                                                  float4* __restrict__ out, int nq){
  int t = blockIdx.x*256 + threadIdx.x;
  if (t >= nq) return;
  int l = (t*4) & 63;
  u32 v0 = P2[t*2], v1 = P2[t*2+1];
  float4 r;
  r.x = (__uint_as_float((v0 & 0xffffu) << 16) - stats[l+0]) * stats[64+l+0];
  r.y = (__uint_as_float( v0 & 0xffff0000u    ) - stats[l+1]) * stats[64+l+1];
  r.z = (__uint_as_float((v1 & 0xffffu) << 16) - stats[l+2]) * stats[64+l+2];
  r.w = (__uint_as_float( v1 & 0xffff0000u    ) - stats[l+3]) * stats[64+l+3];
  out[t] = r;
}

// ---------------- launcher ----------------
extern "C" void kernel_launch(void* const* d_in, const int* in_sizes, int n_in,
                              void* d_out, int out_size, void* d_ws, size_t ws_size,
                              hipStream_t stream)
{
  const float* x      = (const float*)d_in[0];
  const float* Wl[3]  = {(const float*)d_in[1], (const float*)d_in[7],  (const float*)d_in[13]};
  const float* asl[3] = {(const float*)d_in[2], (const float*)d_in[8],  (const float*)d_in[14]};
  const float* adl[3] = {(const float*)d_in[3], (const float*)d_in[9],  (const float*)d_in[15]};
  const float* bl[3]  = {(const float*)d_in[4], (const float*)d_in[10], (const float*)d_in[16]};
  const int*   el[3]  = {(const int*)d_in[5],   (const int*)d_in[11],   (const int*)d_in[17]};

  const int NS[4]  = {4096, 2048, 1024, 512};
  const int EPB[3] = {32768, 16384, 8192};
  const int LOG2NS[3] = {12, 11, 10};
  const int ECAP[3] = {32768+4*4096, 16384+4*2048, 8192+4*1024};  // 49152, 24576, 12288
  const int BATCH = 256;

  char* ws = (char*)d_ws;
  size_t off = 0;
  auto alloc = [&](size_t bytes)->char*{
    char* p = ws + off; off += (bytes + 255) & ~(size_t)255; return p;
  };

  u16*   hbuf    = (u16*)alloc((size_t)BATCH*NS[0]*64*2);            // 128 MB
  u16*   Pbuf    = (u16*)alloc((size_t)BATCH*NS[1]*64*2);            //  64 MB
  u32*   epack   = (u32*)alloc(((size_t)BATCH*ECAP[0] + 64)*4);      //  50 MB
  float* als     = (float*)alloc((size_t)BATCH*NS[0]*4);             //   4 MB
  float* ald     = (float*)alloc((size_t)BATCH*NS[0]*4);             //   4 MB
  float* scratch = (float*)alloc(256*128*4);
  float* stats   = (float*)alloc(128*4);
  u16*   wswz    = (u16*)alloc(10*64*8*2);
  float* cvec    = (float*)alloc(128*4);
  int* counts_all = (int*)alloc((size_t)(NS[0]+NS[1]+NS[2])*4);
  int* cursor_all = (int*)alloc((size_t)(NS[0]+NS[1]+NS[2])*4);
  int *counts[3], *cursor[3], *indptr2[3];
  u32* ell_sd[3];
  u16* perm[3];
  counts[0]=counts_all; counts[1]=counts_all+NS[0]; counts[2]=counts_all+NS[0]+NS[1];
  cursor[0]=cursor_all; cursor[1]=cursor_all+NS[0]; cursor[2]=cursor_all+NS[0]+NS[1];
  for (int i=0;i<3;i++){
    indptr2[i] = (int*)alloc((size_t)(NS[i]+1)*4);
    ell_sd[i]  = (u32*)alloc((size_t)(ECAP[i]+16)*4);
    perm[i]    = (u16*)alloc((size_t)NS[i]);      // NS/2 pairs * 2B
  }
  if (off > ws_size) return;

  // ---- build ----
  int ctot = NS[0]+NS[1]+NS[2];
  {
    dim3 ginit((ECAP[0]+16+255)/256, 4);
    init_k<<<ginit, 256, 0, stream>>>(counts_all, ell_sd[0], ell_sd[1], ell_sd[2],
                                      ctot, ECAP[0]+16, ECAP[1]+16, ECAP[2]+16);
    dim3 ghist(EPB[0]/256, 3);
    hist_all_k<<<ghist, 256, 0, stream>>>(el[0], el[1], el[2], counts[0], counts[1], counts[2],
                                          EPB[0], EPB[1], EPB[2]);
    scan_all_k<<<3, 1024, 0, stream>>>(counts[0], counts[1], counts[2],
                                       indptr2[0], indptr2[1], indptr2[2],
                                       cursor[0], cursor[1], cursor[2],
                                       ell_sd[0], ell_sd[1], ell_sd[2],
                                       NS[0], NS[1], NS[2]);
    scatter_all_k<<<ghist, 256, 0, stream>>>(el[0], el[1], el[2],
                                             cursor[0], cursor[1], cursor[2],
                                             ell_sd[0], ell_sd[1], ell_sd[2],
                                             EPB[0], EPB[1], EPB[2]);
    pairsort_k<<<3, 1024, 0, stream>>>(counts[0], counts[1], counts[2],
                                       perm[0], perm[1], perm[2],
                                       NS[0]/2, NS[1]/2, NS[2]/2);
  }

  // ---- layers ----
  for (int i=0;i<3;i++){
    int ntot = BATCH*NS[i];

    if (i==0){
      gemm3_k<<<1024, 256, 0, stream>>>(x, Wl[0], asl[0], adl[0], hbuf, als, ald, ntot/8);
    } else {
      float invN = 1.0f / (float)(BATCH*NS[i]);   // prev pooled rows = BATCH*NS[i-1]/2 = BATCH*NS[i]
      prep_w_k<<<1, 128, 0, stream>>>(Wl[i], asl[i], adl[i], scratch, invN, wswz, cvec);
      gemm64_mfma_k<<<2048, 256, 0, stream>>>(Pbuf, wswz, cvec, hbuf, als, ald, ntot/16);
    }

    dim3 wgrid(ECAP[i]/256, BATCH);
    wfill_k<<<wgrid, 256, 0, stream>>>(ell_sd[i], als, ald, epack, ECAP[i], LOG2NS[i]);

    int nwaves = ntot/8;
    gat_pool_k<<<nwaves/4, 256, 0, stream>>>(hbuf, bl[i], indptr2[i], counts[i], perm[i], epack,
                                             Pbuf, LOG2NS[i], ECAP[i], nwaves);

    bn_stats_k<<<256, 256, 0, stream>>>(Pbuf, scratch, (ntot/2)/1024);
  }

  // final BN: finish stats of layer 2, then materialize into d_out
  bn_finish_k<<<1, 128, 0, stream>>>(scratch, stats, 256, 1.0f/(float)(BATCH*NS[3]));
  int nq = out_size/4;
  bn_apply_k<<<(nq+255)/256, 256, 0, stream>>>((const u32*)Pbuf, stats, (float4*)d_out, nq);
}

// Round 8
// 550.950 us; speedup vs baseline: 4.1327x; 1.1084x over previous
//
#include <hip/hip_runtime.h>
#include <stdint.h>

#define NEG_SLOPE 0.2f
#define BN_EPS 1e-5f

typedef unsigned short u16;
typedef unsigned int   u32;
typedef __attribute__((ext_vector_type(2))) float  v2f;
typedef __attribute__((ext_vector_type(4))) float  f32x4;
typedef __attribute__((ext_vector_type(8))) short  short8;

__device__ __forceinline__ float lrelu(float x){ return fmaxf(x, NEG_SLOPE*x); }
__device__ __forceinline__ float bf2f(u16 u){ return __uint_as_float(((u32)u) << 16); }
__device__ __forceinline__ u16 f2bf(float f){           // round-to-nearest-even
  u32 u = __float_as_uint(f);
  return (u16)((u + 0x7fffu + ((u >> 16) & 1u)) >> 16);
}

// ---------------- build phase ----------------
// y=0: zero counts; y=1..3: fill ell_src[L] with 0xFFFF
__global__ __launch_bounds__(256) void init_k(int* __restrict__ counts, u16* __restrict__ s0,
                                              u16* __restrict__ s1, u16* __restrict__ s2,
                                              int nc, int n0, int n1, int n2){
  int t = blockIdx.x*256 + threadIdx.x;
  int y = blockIdx.y;
  if (y==0){ if (t<nc) counts[t]=0; }
  else {
    u16* sd = (y==1)?s0:(y==2)?s1:s2;
    int n   = (y==1)?n0:(y==2)?n1:n2;
    if (t<n) sd[t]=0xFFFFu;
  }
}

__global__ __launch_bounds__(256) void hist_all_k(const int* __restrict__ el0, const int* __restrict__ el1,
                                                  const int* __restrict__ el2, int* __restrict__ c0,
                                                  int* __restrict__ c1, int* __restrict__ c2,
                                                  int n0, int n1, int n2){
  int t = blockIdx.x*256 + threadIdx.x;
  int L = blockIdx.y;
  const int* dst = (L==0)?(el0+n0):(L==1)?(el1+n1):(el2+n2);
  int* counts    = (L==0)?c0:(L==1)?c1:c2;
  int n          = (L==0)?n0:(L==1)?n1:n2;
  if (t < n) atomicAdd(&counts[dst[t]], 1);
}

// padded scan per layer: row len = (deg+4)&~3 (>= deg+1), self at slot 0
__global__ __launch_bounds__(1024) void scan_all_k(int* __restrict__ c0, int* __restrict__ c1, int* __restrict__ c2,
                         int* __restrict__ ip0, int* __restrict__ ip1, int* __restrict__ ip2,
                         int* __restrict__ cu0, int* __restrict__ cu1, int* __restrict__ cu2,
                         u16* __restrict__ sd0, u16* __restrict__ sd1, u16* __restrict__ sd2,
                         int n0, int n1, int n2){
  int L = blockIdx.x;
  const int* counts = (L==0)?c0:(L==1)?c1:c2;
  int* indptr2      = (L==0)?ip0:(L==1)?ip1:ip2;
  int* cursor       = (L==0)?cu0:(L==1)?cu1:cu2;
  u16* ell_src      = (L==0)?sd0:(L==1)?sd1:sd2;
  int n             = (L==0)?n0:(L==1)?n1:n2;
  __shared__ int part[1024];
  int tid = threadIdx.x;
  int base = tid*4;
  int v0=0,v1=0,v2=0,v3=0;
  if (base+0<n) v0 = (counts[base+0]+4)&~3;
  if (base+1<n) v1 = (counts[base+1]+4)&~3;
  if (base+2<n) v2 = (counts[base+2]+4)&~3;
  if (base+3<n) v3 = (counts[base+3]+4)&~3;
  part[tid] = v0+v1+v2+v3;
  __syncthreads();
  for (int off=1; off<1024; off<<=1){
    int t2 = (tid>=off)?part[tid-off]:0;
    __syncthreads();
    part[tid] += t2;
    __syncthreads();
  }
  int run = (tid>0)?part[tid-1]:0;
  if (base+0<n){ indptr2[base+0]=run; cursor[base+0]=run+1; ell_src[run]=(u16)(base+0); run+=v0; }
  if (base+1<n){ indptr2[base+1]=run; cursor[base+1]=run+1; ell_src[run]=(u16)(base+1); run+=v1; }
  if (base+2<n){ indptr2[base+2]=run; cursor[base+2]=run+1; ell_src[run]=(u16)(base+2); run+=v2; }
  if (base+3<n){ indptr2[base+3]=run; cursor[base+3]=run+1; ell_src[run]=(u16)(base+3); run+=v3; }
  if (tid==0) indptr2[n] = part[1023];
}

__global__ __launch_bounds__(256) void scatter_all_k(const int* __restrict__ el0, const int* __restrict__ el1,
                         const int* __restrict__ el2, int* __restrict__ cu0, int* __restrict__ cu1,
                         int* __restrict__ cu2, u16* __restrict__ sd0, u16* __restrict__ sd1,
                         u16* __restrict__ sd2, int n0, int n1, int n2){
  int t = blockIdx.x*256 + threadIdx.x;
  int L = blockIdx.y;
  const int* el = (L==0)?el0:(L==1)?el1:el2;
  int* cursor   = (L==0)?cu0:(L==1)?cu1:cu2;
  u16* ell_src  = (L==0)?sd0:(L==1)?sd1:sd2;
  int n         = (L==0)?n0:(L==1)?n1:n2;
  if (t < n){
    int dd = el[n + t];
    int p = atomicAdd(&cursor[dd], 1);
    ell_src[p] = (u16)el[t];
  }
}

// counting sort of pool-pairs by max(deg) -> perm (shared by all graphs)
__global__ __launch_bounds__(1024) void pairsort_k(const int* __restrict__ c0, const int* __restrict__ c1,
                         const int* __restrict__ c2, u16* __restrict__ pm0, u16* __restrict__ pm1,
                         u16* __restrict__ pm2, int np0, int np1, int np2){
  int L = blockIdx.x;
  const int* counts = (L==0)?c0:(L==1)?c1:c2;
  u16* perm = (L==0)?pm0:(L==1)?pm1:pm2;
  int np    = (L==0)?np0:(L==1)?np1:np2;
  __shared__ int hist[64];
  __shared__ int pos[64];
  int t = threadIdx.x;
  if (t < 64) hist[t] = 0;
  __syncthreads();
  for (int p=t; p<np; p+=1024){
    int k = min(max(counts[2*p], counts[2*p+1]), 63);
    atomicAdd(&hist[k], 1);
  }
  __syncthreads();
  if (t == 0){ int run=0; for (int i=0;i<64;i++){ pos[i]=run; run+=hist[i]; } }
  __syncthreads();
  for (int p=t; p<np; p+=1024){
    int k = min(max(counts[2*p], counts[2*p+1]), 63);
    int q = atomicAdd(&pos[k], 1);
    perm[q] = (u16)p;
  }
}

// ---------------- layer-0 GEMM: x[n,3] @ W0[3,64] -> h bf16, al_s, al_d ----------------
__global__ __launch_bounds__(256) void gemm3_k(const float* __restrict__ x, const float* __restrict__ Wg,
                        const float* __restrict__ asrc, const float* __restrict__ adst,
                        u16* __restrict__ h, float* __restrict__ als, float* __restrict__ ald, int nrows8)
{
  const int l = threadIdx.x & 63;
  const int g = l >> 3;
  const int o = l & 7;
  float W0[8], W1[8], W2[8];
  float vs0=0.f,vs1=0.f,vs2=0.f,vd0=0.f,vd1=0.f,vd2=0.f;
  #pragma unroll
  for (int j=0;j<8;j++){
    W0[j] = Wg[      o*8 + j];
    W1[j] = Wg[ 64 + o*8 + j];
    W2[j] = Wg[128 + o*8 + j];
    float as = asrc[o*8 + j], ad = adst[o*8 + j];
    vs0 = fmaf(W0[j], as, vs0); vs1 = fmaf(W1[j], as, vs1); vs2 = fmaf(W2[j], as, vs2);
    vd0 = fmaf(W0[j], ad, vd0); vd1 = fmaf(W1[j], ad, vd1); vd2 = fmaf(W2[j], ad, vd2);
  }
  #pragma unroll
  for (int off=1; off<8; off<<=1){
    vs0 += __shfl_xor(vs0,off); vs1 += __shfl_xor(vs1,off); vs2 += __shfl_xor(vs2,off);
    vd0 += __shfl_xor(vd0,off); vd1 += __shfl_xor(vd1,off); vd2 += __shfl_xor(vd2,off);
  }
  int wv = blockIdx.x*4 + (int)(threadIdx.x>>6);
  int stride = gridDim.x*4;
  for (int blk = wv; blk < nrows8; blk += stride){
    int r = blk*8 + g;
    float x0 = x[(size_t)r*3+0];
    float x1 = x[(size_t)r*3+1];
    float x2 = x[(size_t)r*3+2];
    u32 pk[4];
    #pragma unroll
    for (int j=0;j<8;j+=2){
      float a0 = fmaf(x0, W0[j],   fmaf(x1, W1[j],   x2*W2[j]));
      float a1 = fmaf(x0, W0[j+1], fmaf(x1, W1[j+1], x2*W2[j+1]));
      pk[j>>1] = (u32)f2bf(a0) | ((u32)f2bf(a1) << 16);
    }
    ((int4*)(h + ((size_t)r << 6)))[o] = make_int4((int)pk[0],(int)pk[1],(int)pk[2],(int)pk[3]);
    if (o == 0){
      als[r] = fmaf(x2, vs2, fmaf(x1, vs1, x0*vs0));
      ald[r] = fmaf(x2, vd2, fmaf(x1, vd1, x0*vd0));
    }
  }
}

// ---------------- prep (layers 1/2): BN finish of prev layer + W' frags + als/ald B-tile ----------------
__global__ __launch_bounds__(128) void prep_w_k(const float* __restrict__ W, const float* __restrict__ asrc,
                        const float* __restrict__ adst, const float* __restrict__ scratch, float invN,
                        u16* __restrict__ wswz, float* __restrict__ cvec){
  __shared__ float mean_s[64], rstd_s[64], vs_s[64], vd_s[64], cv_s[64], acc[128];
  int t = threadIdx.x;
  float s = 0.f;
  #pragma unroll 8
  for (int b2=0;b2<256;b2++) s += scratch[b2*128 + t];
  acc[t] = s;
  __syncthreads();
  if (t < 64){
    float m = acc[t]*invN;
    float var = acc[64+t]*invN - m*m;
    mean_s[t] = m; rstd_s[t] = rsqrtf(var + BN_EPS);
  }
  __syncthreads();
  if (t < 64){
    float c = 0.f;
    for (int k=0;k<64;k++) c = fmaf(mean_s[k]*rstd_s[k], W[k*64+t], c);
    cv_s[t] = c; cvec[t] = c;
    float vs = 0.f, vd = 0.f;
    for (int col=0; col<64; col++){
      float wv = W[t*64+col];
      vs = fmaf(wv, asrc[col], vs);
      vd = fmaf(wv, adst[col], vd);
    }
    vs_s[t] = rstd_s[t]*vs; vd_s[t] = rstd_s[t]*vd;
  }
  __syncthreads();
  if (t == 0){
    float cs=0.f, cd=0.f;
    for (int col=0; col<64; col++){ cs = fmaf(cv_s[col], asrc[col], cs); cd = fmaf(cv_s[col], adst[col], cd); }
    cvec[64] = cs; cvec[65] = cd;
  }
  if (t < 64){
    #pragma unroll
    for (int f=0; f<8; f++){
      int tt = f >> 1, ch = f & 1;
      #pragma unroll
      for (int j=0; j<8; j++){
        int k   = ch*32 + (t>>4)*8 + j;
        int col = tt*16 + (t&15);
        wswz[(f*64 + t)*8 + j] = f2bf(rstd_s[k] * W[k*64 + col]);
      }
    }
    #pragma unroll
    for (int f=8; f<10; f++){
      int ch = f - 8;
      #pragma unroll
      for (int j=0; j<8; j++){
        int k = ch*32 + (t>>4)*8 + j;
        int colp = t & 15;
        float val = (colp==0)? vs_s[k] : (colp==1)? vd_s[k] : 0.f;
        wswz[(f*64 + t)*8 + j] = f2bf(val);
      }
    }
  }
}

// ---------------- layers 1/2 GEMM via MFMA: h = P @ W' - c; als/ald via augmented B-tile ----------------
__global__ __launch_bounds__(256) void gemm64_mfma_k(const u16* __restrict__ Pin, const u16* __restrict__ wswz,
                        const float* __restrict__ cvec,
                        u16* __restrict__ h, float* __restrict__ als, float* __restrict__ ald, int nblk16)
{
  const int l = threadIdx.x & 63;
  const int q = l >> 4;
  const int c = l & 15;
  short8 B[10];
  const int4* wsw = (const int4*)wswz;
  #pragma unroll
  for (int f=0; f<10; f++){
    int4 v = wsw[f*64 + l];
    B[f] = *(short8*)&v;
  }
  float cl[4];
  #pragma unroll
  for (int t=0;t<4;t++) cl[t] = cvec[t*16+c];
  const float const_s = cvec[64], const_d = cvec[65];
  int gw = blockIdx.x*4 + (int)(threadIdx.x>>6);
  int stride = gridDim.x*4;
  for (int blk = gw; blk < nblk16; blk += stride){
    size_t rowbase = (size_t)blk*16;
    const int4* arow = (const int4*)(Pin + (rowbase + c)*64);
    int4 a0v = arow[q];
    int4 a1v = arow[4+q];
    short8 A0 = *(short8*)&a0v, A1 = *(short8*)&a1v;
    f32x4 C0={0.f,0.f,0.f,0.f}, C1=C0, C2=C0, C3=C0, C4=C0;
    C0 = __builtin_amdgcn_mfma_f32_16x16x32_bf16(A0, B[0], C0, 0,0,0);
    C0 = __builtin_amdgcn_mfma_f32_16x16x32_bf16(A1, B[1], C0, 0,0,0);
    C1 = __builtin_amdgcn_mfma_f32_16x16x32_bf16(A0, B[2], C1, 0,0,0);
    C1 = __builtin_amdgcn_mfma_f32_16x16x32_bf16(A1, B[3], C1, 0,0,0);
    C2 = __builtin_amdgcn_mfma_f32_16x16x32_bf16(A0, B[4], C2, 0,0,0);
    C2 = __builtin_amdgcn_mfma_f32_16x16x32_bf16(A1, B[5], C2, 0,0,0);
    C3 = __builtin_amdgcn_mfma_f32_16x16x32_bf16(A0, B[6], C3, 0,0,0);
    C3 = __builtin_amdgcn_mfma_f32_16x16x32_bf16(A1, B[7], C3, 0,0,0);
    C4 = __builtin_amdgcn_mfma_f32_16x16x32_bf16(A0, B[8], C4, 0,0,0);
    C4 = __builtin_amdgcn_mfma_f32_16x16x32_bf16(A1, B[9], C4, 0,0,0);
    #pragma unroll
    for (int t=0;t<4;t++){
      f32x4 C = (t==0)?C0:(t==1)?C1:(t==2)?C2:C3;
      #pragma unroll
      for (int reg=0;reg<4;reg++){
        h[(rowbase + q*4 + reg)*64 + t*16 + c] = f2bf(C[reg] - cl[t]);
      }
    }
    if (c == 0){
      #pragma unroll
      for (int reg=0;reg<4;reg++) als[rowbase + q*4 + reg] = C4[reg] - const_s;
    } else if (c == 1){
      #pragma unroll
      for (int reg=0;reg<4;reg++) ald[rowbase + q*4 + reg] = C4[reg] - const_d;
    }
  }
}

// ---------------- GAT gather + inline edge-softmax + bias + relu + pairwise max-pool ----------------
// wave = 8 groups x 8 lanes; group g owns node 2*perm[pairslot]+(g&1).
// 3-deep software pipeline: meta 3 ahead, h+als issued 2 iters before consumption.
// w = exp(lrelu(als[s]+ald[d])) computed inline (no precomputed edge weights).
__global__ __launch_bounds__(256) void gat_pool_k(const u16* __restrict__ h, const float* __restrict__ bias,
                      const int* __restrict__ indptr2, const int* __restrict__ counts,
                      const u16* __restrict__ perm, const u16* __restrict__ ell_src,
                      const float* __restrict__ als, const float* __restrict__ ald,
                      u16* __restrict__ P, int log2NS, int nwaves)
{
  const int l = threadIdx.x & 63;
  const int g = l >> 3;
  const int o = l & 7;
  const int NB  = gridDim.x;
  const int bid = blockIdx.x;
  const int lb  = (bid & 7) * (NB >> 3) + (bid >> 3);   // XCD swizzle
  const int wv  = lb * 4 + (int)(threadIdx.x >> 6);
  if (wv >= nwaves) return;

  const int wbits = log2NS - 3;
  const int b    = wv >> wbits;
  const int widx = wv & ((1 << wbits) - 1);
  const int pairslot = widx*4 + (g >> 1);
  const int prow = perm[pairslot];
  const int d = 2*prow + (g & 1);
  const int nmask = (1 << log2NS) - 1;
  const int base = b << log2NS;
  const u32* hb = (const u32*)(h + ((size_t)base << 6)) + (o << 2);
  const float* alsg = als + base;

  const int p0  = indptr2[d];
  const int cnt = counts[d] + 1;
  const float ald_d = ald[base + d];

  const float* bp = bias + (o << 3);
  float4 bA = *(const float4*)(bp);
  float4 bB = *(const float4*)(bp + 4);

  v2f a01={0.f,0.f}, a23={0.f,0.f}, a45={0.f,0.f}, a67={0.f,0.f};
  float z = 0.f;

  // prologue: meta for items 0,1,2; h+als for items 0,1
  int m0 = ell_src[p0];
  int m1 = ell_src[p0+1];
  int m2 = ell_src[p0+2];
  int s0i = m0 & nmask;
  const u32* hp0 = hb + ((size_t)s0i << 5);
  u32 h00=hp0[0], h01=hp0[1], h02=hp0[2], h03=hp0[3];
  float al0 = alsg[s0i];
  int s1i = m1 & nmask;
  const u32* hp1 = hb + ((size_t)s1i << 5);
  u32 h10=hp1[0], h11=hp1[1], h12=hp1[2], h13=hp1[3];
  float al1 = alsg[s1i];

  for (int it = 0; it < cnt; ++it){
    // issue h+als for item it+2 (meta m2)
    int s2i = m2 & nmask;
    const u32* hp2 = hb + ((size_t)s2i << 5);
    u32 n0=hp2[0], n1=hp2[1], n2=hp2[2], n3=hp2[3];
    float al2 = alsg[s2i];
    // meta for item it+3
    int m3 = ell_src[p0 + it + 3];
    // consume item it
    float w = (m0 == 0xFFFF) ? 0.f : __expf(lrelu(al0 + ald_d));
    z += w;
    v2f w2 = {w, w};
    a01 += (v2f){ __uint_as_float(h00 << 16), __uint_as_float(h00 & 0xffff0000u) } * w2;
    a23 += (v2f){ __uint_as_float(h01 << 16), __uint_as_float(h01 & 0xffff0000u) } * w2;
    a45 += (v2f){ __uint_as_float(h02 << 16), __uint_as_float(h02 & 0xffff0000u) } * w2;
    a67 += (v2f){ __uint_as_float(h03 << 16), __uint_as_float(h03 & 0xffff0000u) } * w2;
    // shift pipeline
    m0 = m1; m1 = m2; m2 = m3;
    h00=h10; h01=h11; h02=h12; h03=h13; al0 = al1;
    h10=n0;  h11=n1;  h12=n2;  h13=n3;  al1 = al2;
  }

  float rz = __builtin_amdgcn_rcpf(z);
  float q0 = fmaxf(fmaf(a01.x, rz, bA.x), 0.f);
  float q1 = fmaxf(fmaf(a01.y, rz, bA.y), 0.f);
  float q2 = fmaxf(fmaf(a23.x, rz, bA.z), 0.f);
  float q3 = fmaxf(fmaf(a23.y, rz, bA.w), 0.f);
  float q4 = fmaxf(fmaf(a45.x, rz, bB.x), 0.f);
  float q5 = fmaxf(fmaf(a45.y, rz, bB.y), 0.f);
  float q6 = fmaxf(fmaf(a67.x, rz, bB.z), 0.f);
  float q7 = fmaxf(fmaf(a67.y, rz, bB.w), 0.f);
  q0 = fmaxf(q0, __shfl_xor(q0, 8));
  q1 = fmaxf(q1, __shfl_xor(q1, 8));
  q2 = fmaxf(q2, __shfl_xor(q2, 8));
  q3 = fmaxf(q3, __shfl_xor(q3, 8));
  q4 = fmaxf(q4, __shfl_xor(q4, 8));
  q5 = fmaxf(q5, __shfl_xor(q5, 8));
  q6 = fmaxf(q6, __shfl_xor(q6, 8));
  q7 = fmaxf(q7, __shfl_xor(q7, 8));
  if ((g & 1) == 0){
    u32 w0 = (u32)f2bf(q0) | ((u32)f2bf(q1) << 16);
    u32 w1 = (u32)f2bf(q2) | ((u32)f2bf(q3) << 16);
    u32 w2p = (u32)f2bf(q4) | ((u32)f2bf(q5) << 16);
    u32 w3 = (u32)f2bf(q6) | ((u32)f2bf(q7) << 16);
    size_t prowg = ((size_t)b << (log2NS - 1)) + prow;
    ((int4*)(P + (prowg << 6)))[o] = make_int4((int)w0,(int)w1,(int)w2p,(int)w3);
  }
}

// ---------------- BatchNorm stats (stage 1) ----------------
__global__ __launch_bounds__(256) void bn_stats_k(const u16* __restrict__ P, float* __restrict__ scratch, int iters){
  const int l = threadIdx.x & 63;
  int gw = blockIdx.x*4 + (threadIdx.x>>6);
  int GW = gridDim.x*4;
  float s = 0.f, s2 = 0.f;
  #pragma unroll 4
  for (int i = 0; i < iters; i++){
    int r = gw + i*GW;
    float v = bf2f(P[(size_t)r*64 + l]);
    s += v; s2 = fmaf(v, v, s2);
  }
  __shared__ float ls[256], ls2[256];
  ls[threadIdx.x] = s; ls2[threadIdx.x] = s2;
  __syncthreads();
  if (threadIdx.x < 64){
    float S  = ls[threadIdx.x] + ls[threadIdx.x+64] + ls[threadIdx.x+128] + ls[threadIdx.x+192];
    float S2 = ls2[threadIdx.x] + ls2[threadIdx.x+64] + ls2[threadIdx.x+128] + ls2[threadIdx.x+192];
    scratch[blockIdx.x*128 + threadIdx.x] = S;
    scratch[blockIdx.x*128 + 64 + threadIdx.x] = S2;
  }
}

__global__ __launch_bounds__(128) void bn_finish_k(const float* __restrict__ scratch, float* __restrict__ stats,
                                                   int nblocks, float invN){
  __shared__ float accs[128];
  int j = threadIdx.x;
  float s = 0.f;
  #pragma unroll 8
  for (int b=0;b<nblocks;b++) s += scratch[b*128 + j];
  accs[j] = s;
  __syncthreads();
  if (j < 64){
    float m = accs[j]*invN;
    float var = accs[j+64]*invN - m*m;
    stats[j] = m;
    stats[64+j] = rsqrtf(var + BN_EPS);
  }
}

// ---------------- final BN apply: bf16 P -> f32 out ----------------
__global__ __launch_bounds__(256) void bn_apply_k(const u32* __restrict__ P2, const float* __restrict__ stats,
                                                  float4* __restrict__ out, int nq){
  int t = blockIdx.x*256 + threadIdx.x;
  if (t >= nq) return;
  int l = (t*4) & 63;
  u32 v0 = P2[t*2], v1 = P2[t*2+1];
  float4 r;
  r.x = (__uint_as_float((v0 & 0xffffu) << 16) - stats[l+0]) * stats[64+l+0];
  r.y = (__uint_as_float( v0 & 0xffff0000u    ) - stats[l+1]) * stats[64+l+1];
  r.z = (__uint_as_float((v1 & 0xffffu) << 16) - stats[l+2]) * stats[64+l+2];
  r.w = (__uint_as_float( v1 & 0xffff0000u    ) - stats[l+3]) * stats[64+l+3];
  out[t] = r;
}

// ---------------- launcher ----------------
extern "C" void kernel_launch(void* const* d_in, const int* in_sizes, int n_in,
                              void* d_out, int out_size, void* d_ws, size_t ws_size,
                              hipStream_t stream)
{
  const float* x      = (const float*)d_in[0];
  const float* Wl[3]  = {(const float*)d_in[1], (const float*)d_in[7],  (const float*)d_in[13]};
  const float* asl[3] = {(const float*)d_in[2], (const float*)d_in[8],  (const float*)d_in[14]};
  const float* adl[3] = {(const float*)d_in[3], (const float*)d_in[9],  (const float*)d_in[15]};
  const float* bl[3]  = {(const float*)d_in[4], (const float*)d_in[10], (const float*)d_in[16]};
  const int*   el[3]  = {(const int*)d_in[5],   (const int*)d_in[11],   (const int*)d_in[17]};

  const int NS[4]  = {4096, 2048, 1024, 512};
  const int EPB[3] = {32768, 16384, 8192};
  const int LOG2NS[3] = {12, 11, 10};
  const int ECAP[3] = {32768+4*4096, 16384+4*2048, 8192+4*1024};  // 49152, 24576, 12288
  const int BATCH = 256;

  char* ws = (char*)d_ws;
  size_t off = 0;
  auto alloc = [&](size_t bytes)->char*{
    char* p = ws + off; off += (bytes + 255) & ~(size_t)255; return p;
  };

  u16*   hbuf    = (u16*)alloc((size_t)BATCH*NS[0]*64*2);            // 128 MB
  u16*   Pbuf    = (u16*)alloc((size_t)BATCH*NS[1]*64*2);            //  64 MB
  float* als     = (float*)alloc((size_t)BATCH*NS[0]*4);             //   4 MB
  float* ald     = (float*)alloc((size_t)BATCH*NS[0]*4);             //   4 MB
  float* scratch = (float*)alloc(256*128*4);
  float* stats   = (float*)alloc(128*4);
  u16*   wswz    = (u16*)alloc(10*64*8*2);
  float* cvec    = (float*)alloc(128*4);
  int* counts_all = (int*)alloc((size_t)(NS[0]+NS[1]+NS[2])*4);
  int* cursor_all = (int*)alloc((size_t)(NS[0]+NS[1]+NS[2])*4);
  int *counts[3], *cursor[3], *indptr2[3];
  u16* ell_src[3];
  u16* perm[3];
  counts[0]=counts_all; counts[1]=counts_all+NS[0]; counts[2]=counts_all+NS[0]+NS[1];
  cursor[0]=cursor_all; cursor[1]=cursor_all+NS[0]; cursor[2]=cursor_all+NS[0]+NS[1];
  for (int i=0;i<3;i++){
    indptr2[i] = (int*)alloc((size_t)(NS[i]+1)*4);
    ell_src[i] = (u16*)alloc((size_t)(ECAP[i]+16)*2);
    perm[i]    = (u16*)alloc((size_t)NS[i]);      // NS/2 pairs * 2B
  }
  if (off > ws_size) return;

  // ---- build ----
  int ctot = NS[0]+NS[1]+NS[2];
  {
    dim3 ginit((ECAP[0]+16+255)/256, 4);
    init_k<<<ginit, 256, 0, stream>>>(counts_all, ell_src[0], ell_src[1], ell_src[2],
                                      ctot, ECAP[0]+16, ECAP[1]+16, ECAP[2]+16);
    dim3 ghist(EPB[0]/256, 3);
    hist_all_k<<<ghist, 256, 0, stream>>>(el[0], el[1], el[2], counts[0], counts[1], counts[2],
                                          EPB[0], EPB[1], EPB[2]);
    scan_all_k<<<3, 1024, 0, stream>>>(counts[0], counts[1], counts[2],
                                       indptr2[0], indptr2[1], indptr2[2],
                                       cursor[0], cursor[1], cursor[2],
                                       ell_src[0], ell_src[1], ell_src[2],
                                       NS[0], NS[1], NS[2]);
    scatter_all_k<<<ghist, 256, 0, stream>>>(el[0], el[1], el[2],
                                             cursor[0], cursor[1], cursor[2],
                                             ell_src[0], ell_src[1], ell_src[2],
                                             EPB[0], EPB[1], EPB[2]);
    pairsort_k<<<3, 1024, 0, stream>>>(counts[0], counts[1], counts[2],
                                       perm[0], perm[1], perm[2],
                                       NS[0]/2, NS[1]/2, NS[2]/2);
  }

  // ---- layers ----
  for (int i=0;i<3;i++){
    int ntot = BATCH*NS[i];

    if (i==0){
      gemm3_k<<<1024, 256, 0, stream>>>(x, Wl[0], asl[0], adl[0], hbuf, als, ald, ntot/8);
    } else {
      float invN = 1.0f / (float)(BATCH*NS[i]);   // prev pooled rows = BATCH*NS[i-1]/2 = BATCH*NS[i]
      prep_w_k<<<1, 128, 0, stream>>>(Wl[i], asl[i], adl[i], scratch, invN, wswz, cvec);
      gemm64_mfma_k<<<2048, 256, 0, stream>>>(Pbuf, wswz, cvec, hbuf, als, ald, ntot/16);
    }

    int nwaves = ntot/8;
    gat_pool_k<<<nwaves/4, 256, 0, stream>>>(hbuf, bl[i], indptr2[i], counts[i], perm[i],
                                             ell_src[i], als, ald,
                                             Pbuf, LOG2NS[i], nwaves);

    bn_stats_k<<<256, 256, 0, stream>>>(Pbuf, scratch, (ntot/2)/1024);
  }

  // final BN: finish stats of layer 2, then materialize into d_out
  bn_finish_k<<<1, 128, 0, stream>>>(scratch, stats, 256, 1.0f/(float)(BATCH*NS[3]));
  int nq = out_size/4;
  bn_apply_k<<<(nq+255)/256, 256, 0, stream>>>((const u32*)Pbuf, stats, (float4*)d_out, nq);
}